// Round 13
// baseline (231.580 us; speedup 1.0000x reference)
//
#include <hip/hip_runtime.h>
#include <hip/hip_bf16.h>
#include <math.h>

// Problem constants (from reference)
constexpr int NN  = 50000;          // nodes
constexpr int NE  = 800000;         // edges (before self loops)
constexpr int EP  = NE + NN;        // edges + self loops = 850000
constexpr int FIN = 512;
constexpr int NH  = 8;
constexpr int NC  = 32;
constexpr int HC  = NH * NC;        // 256
constexpr int CLS = 40;
constexpr int CLSP = 48;            // padded classes for MFMA
constexpr int NGB = (NN + 63) / 64; // 782 gemm blocks
constexpr int NSB = 1024;           // scatter blocks (grid-stride)

typedef __attribute__((ext_vector_type(8))) __bf16 bf16x8;
typedef __attribute__((ext_vector_type(4))) __bf16 bf16x4;
typedef __attribute__((ext_vector_type(4))) float f32x4;
typedef __attribute__((ext_vector_type(2))) float f32x2;

__device__ inline bf16x8 cvt8(const float4 a, const float4 b) {
  bf16x8 o;
  o[0] = (__bf16)a.x; o[1] = (__bf16)a.y; o[2] = (__bf16)a.z; o[3] = (__bf16)a.w;
  o[4] = (__bf16)b.x; o[5] = (__bf16)b.y; o[6] = (__bf16)b.z; o[7] = (__bf16)b.w;
  return o;
}

__device__ inline bf16x8 cvt8v(const f32x4 a, const f32x4 b) {
  bf16x8 o;
  o[0] = (__bf16)a.x; o[1] = (__bf16)a.y; o[2] = (__bf16)a.z; o[3] = (__bf16)a.w;
  o[4] = (__bf16)b.x; o[5] = (__bf16)b.y; o[6] = (__bf16)b.z; o[7] = (__bf16)b.w;
  return o;
}

__device__ inline unsigned char to_fp8(float f) {
  int pk = __builtin_amdgcn_cvt_pk_fp8_f32(f, f, 0, false);
  return (unsigned char)(pk & 0xff);
}

// ---------------------------------------------------------------------------
// CSR build: histogram -> scan -> scatter-by-cursor (scatter fused w/ gemm1)
// ---------------------------------------------------------------------------
__global__ void k_hist(const int* __restrict__ ei, int* __restrict__ deg) {
  int e = blockIdx.x * 256 + threadIdx.x;
  if (e >= EP) return;
  int d = (e < NE) ? ei[NE + e] : (e - NE);
  atomicAdd(&deg[d], 1);
}

__global__ __launch_bounds__(1024) void k_scan1(const int* __restrict__ deg,
                                                int* __restrict__ rowptr1,
                                                int* __restrict__ bsum, int n) {
  __shared__ int sm[1024];
  int i = blockIdx.x * 1024 + threadIdx.x;
  int v = (i < n) ? deg[i] : 0;
  sm[threadIdx.x] = v;
  __syncthreads();
  for (int off = 1; off < 1024; off <<= 1) {
    int t = (threadIdx.x >= off) ? sm[threadIdx.x - off] : 0;
    __syncthreads();
    sm[threadIdx.x] += t;
    __syncthreads();
  }
  if (i < n) rowptr1[i] = sm[threadIdx.x];
  if (threadIdx.x == 1023) bsum[blockIdx.x] = sm[1023];
}

// wave-parallel exclusive scan of nb (<=64) block sums
__global__ void k_scan2(int* __restrict__ bsum, int nb) {
  int lane = threadIdx.x;
  int v = (lane < nb) ? bsum[lane] : 0;
#pragma unroll
  for (int off = 1; off < 64; off <<= 1) {
    int t = __shfl_up(v, off);
    if (lane >= off) v += t;
  }
  int ex = __shfl_up(v, 1);
  if (lane == 0) ex = 0;
  if (lane < nb) bsum[lane] = ex;
}

// adds block offsets; also initializes cursor[] = row start (for scatter)
__global__ void k_scan3(int* __restrict__ rowptr, const int* __restrict__ bsum,
                        int* __restrict__ cursor, int n) {
  int i = blockIdx.x * 256 + threadIdx.x;
  if (i == 0) { rowptr[0] = 0; cursor[0] = 0; }
  if (i < n) {
    int v = rowptr[i + 1] + bsum[i >> 10];
    rowptr[i + 1] = v;
    if (i + 1 < n) cursor[i + 1] = v;
  }
}

// ---------------------------------------------------------------------------
// Weight prep (merged): W1 [512][256] -> Wt [256][512] bf16;
//                       W2 [256][40]  -> W2t [48][256] bf16 (zero-padded)
// ---------------------------------------------------------------------------
__global__ void k_cvt_w(const float* __restrict__ W1, const float* __restrict__ W2,
                        __bf16* __restrict__ Wt, __bf16* __restrict__ W2t) {
  int t = blockIdx.x * 256 + threadIdx.x;
  if (t < HC * (FIN / 8)) {                      // 256 * 64
    int c = t >> 6, kq = (t & 63) * 8;
    bf16x8 o;
#pragma unroll
    for (int j = 0; j < 8; ++j) o[j] = (__bf16)W1[(size_t)(kq + j) * HC + c];
    *(bf16x8*)&Wt[(size_t)c * FIN + kq] = o;
  } else {
    int u = t - HC * (FIN / 8);
    if (u < CLSP * HC) {                         // 48 * 256
      int c = u >> 8, k = u & 255;
      W2t[u] = (c < CLS) ? (__bf16)W2[(size_t)k * CLS + c] : (__bf16)0.f;
    }
  }
}

// ---------------------------------------------------------------------------
// FUSED: blocks [0,NGB) = GEMM1; blocks [NGB,NGB+NSB) = CSR scatter.
// GEMM: BM=64, BN=256, 4 waves. X staged as fp32 panel via global_load_lds
// width=16 in 8 chunks of 64 fp32/row (16 KB each, double-buffered 32 KB) --
// ~16KB/block of X in flight (Little's law fix). LDS slot-XOR swizzle on the
// read; inverse-swizzled per-lane global source. fp32->bf16 cvt at read time.
// B direct-from-L2 Wt. fp8 out + fused alpha1.
// ---------------------------------------------------------------------------
__global__ __launch_bounds__(256) void k_gemm1_scatter(
    const float* __restrict__ X, const __bf16* __restrict__ Wt,
    const float* __restrict__ a_s1, const float* __restrict__ a_d1,
    unsigned char* __restrict__ Hout, float* __restrict__ asrc1,
    float* __restrict__ adst1,
    const int* __restrict__ ei, int* __restrict__ cursor,
    unsigned short* __restrict__ srcS) {
  __shared__ __align__(16) float Xp[2][4096];   // 2 x 16 KB
  const int tid = threadIdx.x;

  if (blockIdx.x >= NGB) {
    // ---------------- scatter half ----------------
    int base = (blockIdx.x - NGB) * 256 + tid;
    for (int e = base; e < EP; e += NSB * 256) {
      int s, d;
      if (e < NE) { s = ei[e]; d = ei[NE + e]; } else { s = d = e - NE; }
      int p = atomicAdd(&cursor[d], 1);
      srcS[p] = (unsigned short)s;
    }
    return;
  }

  // ---------------- GEMM half ----------------
  const int lane = tid & 63;
  const int w    = tid >> 6;              // wave 0..3
  const int wn   = w * 64;
  const int bm   = blockIdx.x * 64;
  const int l15  = lane & 15, lg = lane >> 4;

  // staging geometry: inst j (w*4+jj) covers rows 4j..4j+3 (256B each);
  // lane l -> row 4j+(l>>4), slot (l&15)>>1, half l&1.
  // LDS[row][slot] holds global slot (slot ^ (row&7)) -> fetch inverse.
  const int srow_l  = (lane >> 4);            // row within inst 0..3
  const int sslot   = (l15 >> 1);             // slot 0..7
  const int shalf   = (lane & 1);

  f32x4 acc[4][4] = {};

  // issue chunk c into buffer buf
  auto issue = [&](int c, int buf) {
#pragma unroll
    for (int jj = 0; jj < 4; ++jj) {
      const int j = w * 4 + jj;               // inst 0..15
      const int row_l = 4 * j + srow_l;       // 0..63
      const int rowG = min(bm + row_l, NN - 1);
      const int g = sslot ^ (row_l & 7);      // inverse swizzle
      const float* src = X + (size_t)rowG * FIN + c * 64 + g * 8 + shalf * 4;
      __builtin_amdgcn_global_load_lds(
          (const __attribute__((address_space(1))) void*)src,
          (__attribute__((address_space(3))) void*)(&Xp[buf][j * 256]), 16, 0, 0);
    }
  };

  issue(0, 0);
  for (int c = 0; c < 8; ++c) {
    const int cur = c & 1;
    __syncthreads();                          // drains gl_lds for buf[cur]
    if (c < 7) issue(c + 1, cur ^ 1);

#pragma unroll
    for (int kh = 0; kh < 2; ++kh) {
      const int kb = lg + 4 * kh;             // 0..7
      bf16x8 bv[4];
#pragma unroll
      for (int ni = 0; ni < 4; ++ni)
        bv[ni] = *(const bf16x8*)(Wt + (size_t)(wn + ni * 16 + l15) * FIN
                                     + c * 64 + kb * 8);
#pragma unroll
      for (int mi = 0; mi < 4; ++mi) {
        int r = mi * 16 + l15;
        int fo = r * 64 + ((kb ^ (r & 7)) << 3);
        f32x4 alo = *(const f32x4*)&Xp[cur][fo];
        f32x4 ahi = *(const f32x4*)&Xp[cur][fo + 4];
        bf16x8 av = cvt8v(alo, ahi);
#pragma unroll
        for (int ni = 0; ni < 4; ++ni)
          acc[mi][ni] = __builtin_amdgcn_mfma_f32_16x16x32_bf16(
              av, bv[ni], acc[mi][ni], 0, 0, 0);
      }
    }
    __syncthreads();
  }

  // ---- fused alpha1 (heads 2w, 2w+1) ----
  const int hbase = 2 * w;
#pragma unroll
  for (int hh = 0; hh < 2; ++hh) {
    float asA = a_s1[(hbase + hh) * NC + l15];
    float asB = a_s1[(hbase + hh) * NC + 16 + l15];
    float adA = a_d1[(hbase + hh) * NC + l15];
    float adB = a_d1[(hbase + hh) * NC + 16 + l15];
    float vs = 0.f, vd = 0.f;
#pragma unroll
    for (int mi = 0; mi < 4; ++mi) {
#pragma unroll
      for (int r = 0; r < 4; ++r) {
        float ps = acc[mi][2 * hh][r] * asA + acc[mi][2 * hh + 1][r] * asB;
        float pd = acc[mi][2 * hh][r] * adA + acc[mi][2 * hh + 1][r] * adB;
#pragma unroll
        for (int off = 1; off < 16; off <<= 1) {
          ps += __shfl_xor(ps, off, 64);
          pd += __shfl_xor(pd, off, 64);
        }
        if (l15 == mi * 4 + r) { vs = ps; vd = pd; }
      }
    }
    int rw = bm + (l15 >> 2) * 16 + lg * 4 + (l15 & 3);
    if (rw < NN) {
      asrc1[(size_t)rw * NH + hbase + hh] = vs;
      adst1[(size_t)rw * NH + hbase + hh] = vd;
    }
  }

  // ---- h1 store as fp8 ----
#pragma unroll
  for (int mi = 0; mi < 4; ++mi) {
#pragma unroll
    for (int ni = 0; ni < 4; ++ni) {
      int col = wn + ni * 16 + l15;
#pragma unroll
      for (int r = 0; r < 4; ++r) {
        int row = bm + mi * 16 + lg * 4 + r;
        if (row < NN) Hout[(size_t)row * HC + col] = to_fp8(acc[mi][ni][r]);
      }
    }
  }
}

// ---------------------------------------------------------------------------
// agg1: one wave per dst node; lanes cover 256 channels (fp8x4 = 4B/lane).
// Exp-dedup weight phase + 8-deep gather MLP. bf16 output.
// ---------------------------------------------------------------------------
__global__ __launch_bounds__(256) void k_agg1(const unsigned char* __restrict__ h1f8,
                                              const float* __restrict__ asrc,
                                              const float* __restrict__ adst,
                                              const unsigned short* __restrict__ srcS,
                                              const int* __restrict__ rowptr,
                                              const float* __restrict__ b1,
                                              __bf16* __restrict__ helu) {
  int wave = (blockIdx.x * 256 + threadIdx.x) >> 6;
  int lane = threadIdx.x & 63;
  if (wave >= NN) return;
  int lo = rowptr[wave], hi = rowptr[wave + 1];
  int head = lane >> 3;                 // consumer head (channels)
  int hw   = lane & 7;                  // producer head (weight phase)
  float adstv = adst[wave * NH + head]; // for tail
  float ad2   = adst[wave * NH + hw];   // for weight phase
  float4 acc = {0.f, 0.f, 0.f, 0.f};
  float den = 0.f;

  for (int base = lo; base < hi; base += 64) {
    int cnt = hi - base; if (cnt > 64) cnt = 64;
    int sv = (lane < cnt) ? (int)srcS[base + lane] : 0;
    int j = 0;
    for (; j + 8 <= cnt; j += 8) {
      // weight phase: lane = eg*8 + hw computes w(edge j+eg, head hw)
      int se = __shfl(sv, j + head);    // head == lane>>3 == eg
      float v = asrc[se * NH + hw] + ad2;
      v = v > 0.f ? v : 0.2f * v;
      float wv = __expf(v);
      // gather phase (4 B per lane per edge)
      int s[8]; unsigned int hv[8];
#pragma unroll
      for (int u = 0; u < 8; ++u) s[u] = __shfl(sv, j + u);
#pragma unroll
      for (int u = 0; u < 8; ++u)
        hv[u] = *(const unsigned int*)&h1f8[(size_t)s[u] * HC + lane * 4];
      // consume
#pragma unroll
      for (int u = 0; u < 8; ++u) {
        float wu = __shfl(wv, u * 8 + head);
        f32x2 lo2 = __builtin_amdgcn_cvt_pk_f32_fp8(hv[u], false);
        f32x2 hi2 = __builtin_amdgcn_cvt_pk_f32_fp8(hv[u], true);
        acc.x += wu * lo2.x;
        acc.y += wu * lo2.y;
        acc.z += wu * hi2.x;
        acc.w += wu * hi2.y;
        den += wu;
      }
    }
    for (; j < cnt; ++j) {
      int s = __shfl(sv, j);
      float v = asrc[s * NH + head] + adstv;
      v = v > 0.f ? v : 0.2f * v;
      float w = __expf(v);
      unsigned int hv = *(const unsigned int*)&h1f8[(size_t)s * HC + lane * 4];
      f32x2 lo2 = __builtin_amdgcn_cvt_pk_f32_fp8(hv, false);
      f32x2 hi2 = __builtin_amdgcn_cvt_pk_f32_fp8(hv, true);
      acc.x += w * lo2.x;
      acc.y += w * lo2.y;
      acc.z += w * hi2.x;
      acc.w += w * hi2.y;
      den += w;
    }
  }

  float inv = 1.f / (den + 1e-16f);
  float4 bb = *(const float4*)&b1[lane * 4];
  float o[4] = {acc.x * inv + bb.x, acc.y * inv + bb.y,
                acc.z * inv + bb.z, acc.w * inv + bb.w};
  bf16x4 ov;
#pragma unroll
  for (int j2 = 0; j2 < 4; ++j2) {
    float e = o[j2] > 0.f ? o[j2] : expm1f(o[j2]);
    ov[j2] = (__bf16)e;
  }
  *(bf16x4*)&helu[(size_t)wave * HC + lane * 4] = ov;
}

// ---------------------------------------------------------------------------
// GEMM2 (bf16 MFMA): h2b[NN,40] = helu[NN,256] @ W2t^T (48 padded cols)
// Fused alpha2: wave holds all 48 cols -> asrc2/adst2 from fp32 acc.
// ---------------------------------------------------------------------------
__global__ __launch_bounds__(256) void k_gemm2m(const __bf16* __restrict__ A,
                                                const __bf16* __restrict__ W2t,
                                                const float* __restrict__ a_s2,
                                                const float* __restrict__ a_d2,
                                                __bf16* __restrict__ Hout,
                                                float* __restrict__ asrc2,
                                                float* __restrict__ adst2) {
  __shared__ __align__(16) __bf16 As[128 * 8 * 8];       // 16 KB
  __shared__ __align__(16) __bf16 Bsh[CLSP * 33 * 8];    // 25.3 KB padded
  const int tid  = threadIdx.x;
  const int lane = tid & 63;
  const int w    = tid >> 6;
  const int wm   = w * 32;
  const int bm   = blockIdx.x * 128;

  const int l3 = lane >> 3;
  const int l7 = lane & 7;
  const int kb_src = l7 ^ l3;

  for (int s = tid; s < CLSP * 32; s += 256) {
    int c = s >> 5, kb = s & 31;
    *(bf16x8*)(Bsh + (size_t)(c * 33 + kb) * 8) =
        *(const bf16x8*)(W2t + (size_t)c * HC + kb * 8);
  }

  f32x4 acc[2][3] = {};

  for (int step = 0; step < 4; ++step) {
    const int k0 = step * 64;
#pragma unroll
    for (int q = 0; q < 4; ++q) {
      const int inst = w * 4 + q;
      const int r = inst * 8 + l3;
      const int arow = min(bm + r, NN - 1);
      const __bf16* ga = A + (size_t)arow * HC + k0 + kb_src * 8;
      __builtin_amdgcn_global_load_lds(
          (const __attribute__((address_space(1))) void*)ga,
          (__attribute__((address_space(3))) void*)(As + inst * 512), 16, 0, 0);
    }
    __syncthreads();

    const int l15 = lane & 15, lg = lane >> 4;
#pragma unroll
    for (int kh = 0; kh < 2; ++kh) {
      const int kbl = lg + 4 * kh;
      const int kbg = step * 8 + kbl;
      bf16x8 av[2], bv[3];
#pragma unroll
      for (int mi = 0; mi < 2; ++mi) {
        int r = wm + mi * 16 + l15;
        av[mi] = *(const bf16x8*)(As + (size_t)(r * 8 + (kbl ^ (r & 7))) * 8);
      }
#pragma unroll
      for (int ni = 0; ni < 3; ++ni) {
        int c = ni * 16 + l15;
        bv[ni] = *(const bf16x8*)(Bsh + (size_t)(c * 33 + kbg) * 8);
      }
#pragma unroll
      for (int mi = 0; mi < 2; ++mi)
#pragma unroll
        for (int ni = 0; ni < 3; ++ni)
          acc[mi][ni] = __builtin_amdgcn_mfma_f32_16x16x32_bf16(
              av[mi], bv[ni], acc[mi][ni], 0, 0, 0);
    }
    __syncthreads();
  }

  const int l15 = lane & 15, lg = lane >> 4;

  // ---- fused alpha2 ----
  {
    int c0 = l15, c1 = 16 + l15, c2 = 32 + l15;
    float as0 = a_s2[c0], as1 = a_s2[c1], as2v = (c2 < CLS) ? a_s2[c2] : 0.f;
    float ad0 = a_d2[c0], ad1 = a_d2[c1], ad2v = (c2 < CLS) ? a_d2[c2] : 0.f;
    float vs = 0.f, vd = 0.f;
#pragma unroll
    for (int mi = 0; mi < 2; ++mi) {
#pragma unroll
      for (int r = 0; r < 4; ++r) {
        float ps = acc[mi][0][r] * as0 + acc[mi][1][r] * as1 + acc[mi][2][r] * as2v;
        float pd = acc[mi][0][r] * ad0 + acc[mi][1][r] * ad1 + acc[mi][2][r] * ad2v;
#pragma unroll
        for (int off = 1; off < 16; off <<= 1) {
          ps += __shfl_xor(ps, off, 64);
          pd += __shfl_xor(pd, off, 64);
        }
        if (l15 == mi * 4 + r) { vs = ps; vd = pd; }
      }
    }
    int rw = bm + wm + (l15 >> 2) * 16 + lg * 4 + (l15 & 3);
    if (l15 < 8 && rw < NN) {
      asrc2[rw] = vs;
      adst2[rw] = vd;
    }
  }

  // ---- h2b store ----
#pragma unroll
  for (int mi = 0; mi < 2; ++mi) {
#pragma unroll
    for (int ni = 0; ni < 3; ++ni) {
      int col = ni * 16 + l15;
      if (col >= CLS) continue;
#pragma unroll
      for (int r = 0; r < 4; ++r) {
        int row = bm + wm + mi * 16 + lg * 4 + r;
        if (row < NN) Hout[(size_t)row * CLS + col] = (__bf16)acc[mi][ni][r];
      }
    }
  }
}

// ---------------------------------------------------------------------------
// agg2: one wave per dst node; lanes 0..39 = classes. Exp-dedup weights;
// fused bias + log_softmax.
// ---------------------------------------------------------------------------
__global__ __launch_bounds__(256) void k_agg2(const __bf16* __restrict__ h2b,
                                              const float* __restrict__ asrc,
                                              const float* __restrict__ adst,
                                              const unsigned short* __restrict__ srcS,
                                              const int* __restrict__ rowptr,
                                              const float* __restrict__ b2,
                                              float* __restrict__ out) {
  int wave = (blockIdx.x * 256 + threadIdx.x) >> 6;
  int lane = threadIdx.x & 63;
  if (wave >= NN) return;
  int lo = rowptr[wave], hi = rowptr[wave + 1];
  bool act = lane < CLS;
  float adstv = adst[wave];
  float acc = 0.f, den = 0.f;

  for (int base = lo; base < hi; base += 64) {
    int cnt = hi - base; if (cnt > 64) cnt = 64;
    int sv = (lane < cnt) ? (int)srcS[base + lane] : 0;
    // weight phase: lane computes weight of its own chunk edge
    float v = asrc[sv] + adstv;
    v = v > 0.f ? v : 0.2f * v;
    float wv = __expf(v);
    int j = 0;
    for (; j + 8 <= cnt; j += 8) {
      int s[8]; float hval[8];
#pragma unroll
      for (int u = 0; u < 8; ++u) s[u] = __shfl(sv, j + u);
#pragma unroll
      for (int u = 0; u < 8; ++u)
        hval[u] = act ? (float)h2b[(size_t)s[u] * CLS + lane] : 0.f;
#pragma unroll
      for (int u = 0; u < 8; ++u) {
        float wu = __shfl(wv, j + u);
        acc += wu * hval[u];
        den += wu;
      }
    }
    for (; j < cnt; ++j) {
      int s = __shfl(sv, j);
      float wu = __shfl(wv, j);
      if (act) acc += wu * (float)h2b[(size_t)s * CLS + lane];
      den += wu;
    }
  }

  float o = act ? (acc / (den + 1e-16f) + b2[lane]) : -INFINITY;
  float m = o;
#pragma unroll
  for (int off = 32; off; off >>= 1) m = fmaxf(m, __shfl_xor(m, off, 64));
  float ex = act ? __expf(o - m) : 0.f;
  float ssum = ex;
#pragma unroll
  for (int off = 32; off; off >>= 1) ssum += __shfl_xor(ssum, off, 64);
  if (act) out[(size_t)wave * CLS + lane] = o - m - logf(ssum);
}

// ---------------------------------------------------------------------------
extern "C" void kernel_launch(void* const* d_in, const int* in_sizes, int n_in,
                              void* d_out, int out_size, void* d_ws, size_t ws_size,
                              hipStream_t stream) {
  const float* x      = (const float*)d_in[0];
  const int*   ei     = (const int*)d_in[1];
  const float* W1     = (const float*)d_in[2];
  const float* a_src1 = (const float*)d_in[3];
  const float* a_dst1 = (const float*)d_in[4];
  const float* b1     = (const float*)d_in[5];
  const float* W2     = (const float*)d_in[6];
  const float* a_src2 = (const float*)d_in[7];
  const float* a_dst2 = (const float*)d_in[8];
  const float* b2     = (const float*)d_in[9];
  float* out = (float*)d_out;

  char* p = (char*)d_ws;
  auto alloc = [&](size_t bytes) {
    char* r = p;
    p += (bytes + 255) & ~size_t(255);
    return r;
  };
  unsigned char* h1f8 = (unsigned char*)alloc((size_t)NN * HC);   // 12.8 MB
  __bf16* helu  = (__bf16*)alloc((size_t)NN * HC * 2);     // 25.6 MB
  __bf16* Wt    = (__bf16*)alloc((size_t)HC * FIN * 2);    // 256 KB
  __bf16* W2t   = (__bf16*)alloc((size_t)CLSP * HC * 2);   // 24 KB
  __bf16* h2b   = (__bf16*)alloc((size_t)NN * CLS * 2);    // 4 MB
  float*  asrc1 = (float*)alloc((size_t)NN * NH * 4);
  float*  adst1 = (float*)alloc((size_t)NN * NH * 4);
  float*  asrc2 = (float*)alloc((size_t)NN * 4);
  float*  adst2 = (float*)alloc((size_t)NN * 4);
  unsigned short* srcS = (unsigned short*)alloc((size_t)EP * 2);  // 1.7 MB
  int*    deg   = (int*)alloc((size_t)NN * 4);
  int*    cursor= (int*)alloc((size_t)NN * 4);
  int*    rowptr= (int*)alloc((size_t)(NN + 1) * 4);
  int*    bsum  = (int*)alloc(256 * 4);

  hipMemsetAsync(deg, 0, (size_t)NN * 4, stream);

  const int nbScan = (NN + 1023) / 1024;  // 49
  k_hist<<<(EP + 255) / 256, 256, 0, stream>>>(ei, deg);
  k_scan1<<<nbScan, 1024, 0, stream>>>(deg, rowptr + 1, bsum, NN);
  k_scan2<<<1, 64, 0, stream>>>(bsum, nbScan);
  k_scan3<<<(NN + 255) / 256, 256, 0, stream>>>(rowptr, bsum, cursor, NN);

  k_cvt_w<<<(HC * (FIN / 8) + CLSP * HC + 255) / 256, 256, 0, stream>>>(W1, W2, Wt, W2t);

  // fused: gemm1 (blocks 0..NGB-1) || csr scatter (blocks NGB..NGB+NSB-1)
  k_gemm1_scatter<<<NGB + NSB, 256, 0, stream>>>(x, Wt, a_src1, a_dst1,
                                                 h1f8, asrc1, adst1,
                                                 ei, cursor, srcS);

  k_agg1<<<(NN + 3) / 4, 256, 0, stream>>>(h1f8, asrc1, adst1, srcS, rowptr, b1, helu);

  k_gemm2m<<<(NN + 127) / 128, 256, 0, stream>>>(helu, W2t, a_src2, a_dst2,
                                                 h2b, asrc2, adst2);
  k_agg2<<<(NN + 3) / 4, 256, 0, stream>>>(h2b, asrc2, adst2, srcS, rowptr, b2, out);
}

// Round 14
// 226.313 us; speedup vs baseline: 1.0233x; 1.0233x over previous
//
#include <hip/hip_runtime.h>
#include <hip/hip_bf16.h>
#include <math.h>

// Problem constants (from reference)
constexpr int NN  = 50000;          // nodes
constexpr int NE  = 800000;         // edges (before self loops)
constexpr int EP  = NE + NN;        // edges + self loops = 850000
constexpr int FIN = 512;
constexpr int NH  = 8;
constexpr int NC  = 32;
constexpr int HC  = NH * NC;        // 256
constexpr int CLS = 40;
constexpr int CLSP = 48;            // padded classes for MFMA
constexpr int NGB = (NN + 63) / 64;     // 782 gemm blocks
constexpr int NSCB = (EP + 255) / 256;  // 3321 scatter blocks (1 edge/thread)
constexpr int CVTW_ITEMS = HC * (FIN / 8) + CLSP * HC;  // 28672
constexpr int CVTW_B = (CVTW_ITEMS + 255) / 256;        // 112

typedef __attribute__((ext_vector_type(8))) __bf16 bf16x8;
typedef __attribute__((ext_vector_type(4))) __bf16 bf16x4;
typedef __attribute__((ext_vector_type(4))) float f32x4;
typedef __attribute__((ext_vector_type(2))) float f32x2;

__device__ inline bf16x8 cvt8v(const f32x4 a, const f32x4 b) {
  bf16x8 o;
  o[0] = (__bf16)a.x; o[1] = (__bf16)a.y; o[2] = (__bf16)a.z; o[3] = (__bf16)a.w;
  o[4] = (__bf16)b.x; o[5] = (__bf16)b.y; o[6] = (__bf16)b.z; o[7] = (__bf16)b.w;
  return o;
}

__device__ inline unsigned char to_fp8(float f) {
  int pk = __builtin_amdgcn_cvt_pk_fp8_f32(f, f, 0, false);
  return (unsigned char)(pk & 0xff);
}

__device__ inline float from_fp8(unsigned char b) {
  f32x2 v = __builtin_amdgcn_cvt_pk_f32_fp8((unsigned)b, false);
  return v.x;
}

// ---------------------------------------------------------------------------
// k_prep: fused deg-histogram (blocks [0,NSCB)) + weight cvt (rest).
// ---------------------------------------------------------------------------
__global__ void k_prep(const int* __restrict__ ei, int* __restrict__ deg,
                       const float* __restrict__ W1, const float* __restrict__ W2,
                       __bf16* __restrict__ Wt, __bf16* __restrict__ W2t) {
  if (blockIdx.x < NSCB) {
    int e = blockIdx.x * 256 + threadIdx.x;
    if (e >= EP) return;
    int d = (e < NE) ? ei[NE + e] : (e - NE);
    atomicAdd(&deg[d], 1);
    return;
  }
  int t = (blockIdx.x - NSCB) * 256 + threadIdx.x;
  if (t < HC * (FIN / 8)) {                      // 256 * 64
    int c = t >> 6, kq = (t & 63) * 8;
    bf16x8 o;
#pragma unroll
    for (int j = 0; j < 8; ++j) o[j] = (__bf16)W1[(size_t)(kq + j) * HC + c];
    *(bf16x8*)&Wt[(size_t)c * FIN + kq] = o;
  } else if (t < CVTW_ITEMS) {
    int u = t - HC * (FIN / 8);                  // 48 * 256
    int c = u >> 8, k = u & 255;
    W2t[u] = (c < CLS) ? (__bf16)W2[(size_t)k * CLS + c] : (__bf16)0.f;
  }
}

__global__ __launch_bounds__(1024) void k_scan1(const int* __restrict__ deg,
                                                int* __restrict__ rowptr1,
                                                int* __restrict__ bsum, int n) {
  __shared__ int sm[1024];
  int i = blockIdx.x * 1024 + threadIdx.x;
  int v = (i < n) ? deg[i] : 0;
  sm[threadIdx.x] = v;
  __syncthreads();
  for (int off = 1; off < 1024; off <<= 1) {
    int t = (threadIdx.x >= off) ? sm[threadIdx.x - off] : 0;
    __syncthreads();
    sm[threadIdx.x] += t;
    __syncthreads();
  }
  if (i < n) rowptr1[i] = sm[threadIdx.x];
  if (threadIdx.x == 1023) bsum[blockIdx.x] = sm[1023];
}

__global__ void k_scan2(int* __restrict__ bsum, int nb) {
  int lane = threadIdx.x;
  int v = (lane < nb) ? bsum[lane] : 0;
#pragma unroll
  for (int off = 1; off < 64; off <<= 1) {
    int t = __shfl_up(v, off);
    if (lane >= off) v += t;
  }
  int ex = __shfl_up(v, 1);
  if (lane == 0) ex = 0;
  if (lane < nb) bsum[lane] = ex;
}

__global__ void k_scan3(int* __restrict__ rowptr, const int* __restrict__ bsum,
                        int* __restrict__ cursor, int n) {
  int i = blockIdx.x * 256 + threadIdx.x;
  if (i == 0) { rowptr[0] = 0; cursor[0] = 0; }
  if (i < n) {
    int v = rowptr[i + 1] + bsum[i >> 10];
    rowptr[i + 1] = v;
    if (i + 1 < n) cursor[i + 1] = v;
  }
}

// ---------------------------------------------------------------------------
// FUSED: blocks [0,NGB) = GEMM1; blocks [NGB,NGB+NSCB) = CSR scatter
// (one edge per thread). GEMM: BM=64, BN=256, 4 waves; X staged as fp32
// panel via global_load_lds w=16, double-buffered 32 KB. B direct from L2.
// ---------------------------------------------------------------------------
__global__ __launch_bounds__(256) void k_gemm1_scatter(
    const float* __restrict__ X, const __bf16* __restrict__ Wt,
    const float* __restrict__ a_s1, const float* __restrict__ a_d1,
    unsigned char* __restrict__ Hout, float* __restrict__ asrc1,
    float* __restrict__ adst1,
    const int* __restrict__ ei, int* __restrict__ cursor,
    unsigned short* __restrict__ srcS) {
  __shared__ __align__(16) float Xp[2][4096];   // 2 x 16 KB
  const int tid = threadIdx.x;

  if (blockIdx.x >= NGB) {
    int e = (blockIdx.x - NGB) * 256 + tid;
    if (e < EP) {
      int s, d;
      if (e < NE) { s = ei[e]; d = ei[NE + e]; } else { s = d = e - NE; }
      int p = atomicAdd(&cursor[d], 1);
      srcS[p] = (unsigned short)s;
    }
    return;
  }

  const int lane = tid & 63;
  const int w    = tid >> 6;              // wave 0..3
  const int wn   = w * 64;
  const int bm   = blockIdx.x * 64;
  const int l15  = lane & 15, lg = lane >> 4;

  const int srow_l  = (lane >> 4);            // row within inst 0..3
  const int sslot   = (l15 >> 1);             // slot 0..7
  const int shalf   = (lane & 1);

  f32x4 acc[4][4] = {};

  auto issue = [&](int c, int buf) {
#pragma unroll
    for (int jj = 0; jj < 4; ++jj) {
      const int j = w * 4 + jj;               // inst 0..15
      const int row_l = 4 * j + srow_l;       // 0..63
      const int rowG = min(bm + row_l, NN - 1);
      const int g = sslot ^ (row_l & 7);      // inverse swizzle
      const float* src = X + (size_t)rowG * FIN + c * 64 + g * 8 + shalf * 4;
      __builtin_amdgcn_global_load_lds(
          (const __attribute__((address_space(1))) void*)src,
          (__attribute__((address_space(3))) void*)(&Xp[buf][j * 256]), 16, 0, 0);
    }
  };

  issue(0, 0);
  for (int c = 0; c < 8; ++c) {
    const int cur = c & 1;
    __syncthreads();
    if (c < 7) issue(c + 1, cur ^ 1);

#pragma unroll
    for (int kh = 0; kh < 2; ++kh) {
      const int kb = lg + 4 * kh;             // 0..7
      bf16x8 bv[4];
#pragma unroll
      for (int ni = 0; ni < 4; ++ni)
        bv[ni] = *(const bf16x8*)(Wt + (size_t)(wn + ni * 16 + l15) * FIN
                                     + c * 64 + kb * 8);
#pragma unroll
      for (int mi = 0; mi < 4; ++mi) {
        int r = mi * 16 + l15;
        int fo = r * 64 + ((kb ^ (r & 7)) << 3);
        f32x4 alo = *(const f32x4*)&Xp[cur][fo];
        f32x4 ahi = *(const f32x4*)&Xp[cur][fo + 4];
        bf16x8 av = cvt8v(alo, ahi);
#pragma unroll
        for (int ni = 0; ni < 4; ++ni)
          acc[mi][ni] = __builtin_amdgcn_mfma_f32_16x16x32_bf16(
              av, bv[ni], acc[mi][ni], 0, 0, 0);
      }
    }
    __syncthreads();
  }

  // ---- fused alpha1 (heads 2w, 2w+1) ----
  const int hbase = 2 * w;
#pragma unroll
  for (int hh = 0; hh < 2; ++hh) {
    float asA = a_s1[(hbase + hh) * NC + l15];
    float asB = a_s1[(hbase + hh) * NC + 16 + l15];
    float adA = a_d1[(hbase + hh) * NC + l15];
    float adB = a_d1[(hbase + hh) * NC + 16 + l15];
    float vs = 0.f, vd = 0.f;
#pragma unroll
    for (int mi = 0; mi < 4; ++mi) {
#pragma unroll
      for (int r = 0; r < 4; ++r) {
        float ps = acc[mi][2 * hh][r] * asA + acc[mi][2 * hh + 1][r] * asB;
        float pd = acc[mi][2 * hh][r] * adA + acc[mi][2 * hh + 1][r] * adB;
#pragma unroll
        for (int off = 1; off < 16; off <<= 1) {
          ps += __shfl_xor(ps, off, 64);
          pd += __shfl_xor(pd, off, 64);
        }
        if (l15 == mi * 4 + r) { vs = ps; vd = pd; }
      }
    }
    int rw = bm + (l15 >> 2) * 16 + lg * 4 + (l15 & 3);
    if (rw < NN) {
      asrc1[(size_t)rw * NH + hbase + hh] = vs;
      adst1[(size_t)rw * NH + hbase + hh] = vd;
    }
  }

  // ---- h1 store as fp8 ----
#pragma unroll
  for (int mi = 0; mi < 4; ++mi) {
#pragma unroll
    for (int ni = 0; ni < 4; ++ni) {
      int col = wn + ni * 16 + l15;
#pragma unroll
      for (int r = 0; r < 4; ++r) {
        int row = bm + mi * 16 + lg * 4 + r;
        if (row < NN) Hout[(size_t)row * HC + col] = to_fp8(acc[mi][ni][r]);
      }
    }
  }
}

// ---------------------------------------------------------------------------
// agg1: one wave per dst node; fp8x4 gather; exp-dedup; 8-deep MLP.
// ---------------------------------------------------------------------------
__global__ __launch_bounds__(256) void k_agg1(const unsigned char* __restrict__ h1f8,
                                              const float* __restrict__ asrc,
                                              const float* __restrict__ adst,
                                              const unsigned short* __restrict__ srcS,
                                              const int* __restrict__ rowptr,
                                              const float* __restrict__ b1,
                                              __bf16* __restrict__ helu) {
  int wave = (blockIdx.x * 256 + threadIdx.x) >> 6;
  int lane = threadIdx.x & 63;
  if (wave >= NN) return;
  int lo = rowptr[wave], hi = rowptr[wave + 1];
  int head = lane >> 3;
  int hw   = lane & 7;
  float adstv = adst[wave * NH + head];
  float ad2   = adst[wave * NH + hw];
  float4 acc = {0.f, 0.f, 0.f, 0.f};
  float den = 0.f;

  for (int base = lo; base < hi; base += 64) {
    int cnt = hi - base; if (cnt > 64) cnt = 64;
    int sv = (lane < cnt) ? (int)srcS[base + lane] : 0;
    int j = 0;
    for (; j + 8 <= cnt; j += 8) {
      int se = __shfl(sv, j + head);
      float v = asrc[se * NH + hw] + ad2;
      v = v > 0.f ? v : 0.2f * v;
      float wv = __expf(v);
      int s[8]; unsigned int hv[8];
#pragma unroll
      for (int u = 0; u < 8; ++u) s[u] = __shfl(sv, j + u);
#pragma unroll
      for (int u = 0; u < 8; ++u)
        hv[u] = *(const unsigned int*)&h1f8[(size_t)s[u] * HC + lane * 4];
#pragma unroll
      for (int u = 0; u < 8; ++u) {
        float wu = __shfl(wv, u * 8 + head);
        f32x2 lo2 = __builtin_amdgcn_cvt_pk_f32_fp8(hv[u], false);
        f32x2 hi2 = __builtin_amdgcn_cvt_pk_f32_fp8(hv[u], true);
        acc.x += wu * lo2.x;
        acc.y += wu * lo2.y;
        acc.z += wu * hi2.x;
        acc.w += wu * hi2.y;
        den += wu;
      }
    }
    for (; j < cnt; ++j) {
      int s = __shfl(sv, j);
      float v = asrc[s * NH + head] + adstv;
      v = v > 0.f ? v : 0.2f * v;
      float w = __expf(v);
      unsigned int hv = *(const unsigned int*)&h1f8[(size_t)s * HC + lane * 4];
      f32x2 lo2 = __builtin_amdgcn_cvt_pk_f32_fp8(hv, false);
      f32x2 hi2 = __builtin_amdgcn_cvt_pk_f32_fp8(hv, true);
      acc.x += w * lo2.x;
      acc.y += w * lo2.y;
      acc.z += w * hi2.x;
      acc.w += w * hi2.y;
      den += w;
    }
  }

  float inv = 1.f / (den + 1e-16f);
  float4 bb = *(const float4*)&b1[lane * 4];
  float o[4] = {acc.x * inv + bb.x, acc.y * inv + bb.y,
                acc.z * inv + bb.z, acc.w * inv + bb.w};
  bf16x4 ov;
#pragma unroll
  for (int j2 = 0; j2 < 4; ++j2) {
    float e = o[j2] > 0.f ? o[j2] : expm1f(o[j2]);
    ov[j2] = (__bf16)e;
  }
  *(bf16x4*)&helu[(size_t)wave * HC + lane * 4] = ov;
}

// ---------------------------------------------------------------------------
// GEMM2 (bf16 MFMA): h2p[NN,64](fp8 padded rows) = helu @ W2t^T + alpha2.
// ---------------------------------------------------------------------------
__global__ __launch_bounds__(256) void k_gemm2m(const __bf16* __restrict__ A,
                                                const __bf16* __restrict__ W2t,
                                                const float* __restrict__ a_s2,
                                                const float* __restrict__ a_d2,
                                                unsigned char* __restrict__ h2p,
                                                float* __restrict__ asrc2,
                                                float* __restrict__ adst2) {
  __shared__ __align__(16) __bf16 As[128 * 8 * 8];       // 16 KB
  __shared__ __align__(16) __bf16 Bsh[CLSP * 33 * 8];    // 25.3 KB padded
  const int tid  = threadIdx.x;
  const int lane = tid & 63;
  const int w    = tid >> 6;
  const int wm   = w * 32;
  const int bm   = blockIdx.x * 128;

  const int l3 = lane >> 3;
  const int l7 = lane & 7;
  const int kb_src = l7 ^ l3;

  for (int s = tid; s < CLSP * 32; s += 256) {
    int c = s >> 5, kb = s & 31;
    *(bf16x8*)(Bsh + (size_t)(c * 33 + kb) * 8) =
        *(const bf16x8*)(W2t + (size_t)c * HC + kb * 8);
  }

  f32x4 acc[2][3] = {};

  for (int step = 0; step < 4; ++step) {
    const int k0 = step * 64;
#pragma unroll
    for (int q = 0; q < 4; ++q) {
      const int inst = w * 4 + q;
      const int r = inst * 8 + l3;
      const int arow = min(bm + r, NN - 1);
      const __bf16* ga = A + (size_t)arow * HC + k0 + kb_src * 8;
      __builtin_amdgcn_global_load_lds(
          (const __attribute__((address_space(1))) void*)ga,
          (__attribute__((address_space(3))) void*)(As + inst * 512), 16, 0, 0);
    }
    __syncthreads();

    const int l15 = lane & 15, lg = lane >> 4;
#pragma unroll
    for (int kh = 0; kh < 2; ++kh) {
      const int kbl = lg + 4 * kh;
      const int kbg = step * 8 + kbl;
      bf16x8 av[2], bv[3];
#pragma unroll
      for (int mi = 0; mi < 2; ++mi) {
        int r = wm + mi * 16 + l15;
        av[mi] = *(const bf16x8*)(As + (size_t)(r * 8 + (kbl ^ (r & 7))) * 8);
      }
#pragma unroll
      for (int ni = 0; ni < 3; ++ni) {
        int c = ni * 16 + l15;
        bv[ni] = *(const bf16x8*)(Bsh + (size_t)(c * 33 + kbg) * 8);
      }
#pragma unroll
      for (int mi = 0; mi < 2; ++mi)
#pragma unroll
        for (int ni = 0; ni < 3; ++ni)
          acc[mi][ni] = __builtin_amdgcn_mfma_f32_16x16x32_bf16(
              av[mi], bv[ni], acc[mi][ni], 0, 0, 0);
    }
    __syncthreads();
  }

  const int l15 = lane & 15, lg = lane >> 4;

  // ---- fused alpha2 ----
  {
    int c0 = l15, c1 = 16 + l15, c2 = 32 + l15;
    float as0 = a_s2[c0], as1 = a_s2[c1], as2v = (c2 < CLS) ? a_s2[c2] : 0.f;
    float ad0 = a_d2[c0], ad1 = a_d2[c1], ad2v = (c2 < CLS) ? a_d2[c2] : 0.f;
    float vs = 0.f, vd = 0.f;
#pragma unroll
    for (int mi = 0; mi < 2; ++mi) {
#pragma unroll
      for (int r = 0; r < 4; ++r) {
        float ps = acc[mi][0][r] * as0 + acc[mi][1][r] * as1 + acc[mi][2][r] * as2v;
        float pd = acc[mi][0][r] * ad0 + acc[mi][1][r] * ad1 + acc[mi][2][r] * ad2v;
#pragma unroll
        for (int off = 1; off < 16; off <<= 1) {
          ps += __shfl_xor(ps, off, 64);
          pd += __shfl_xor(pd, off, 64);
        }
        if (l15 == mi * 4 + r) { vs = ps; vd = pd; }
      }
    }
    int rw = bm + wm + (l15 >> 2) * 16 + lg * 4 + (l15 & 3);
    if (l15 < 8 && rw < NN) {
      asrc2[rw] = vs;
      adst2[rw] = vd;
    }
  }

  // ---- h2p store (fp8, 64B-padded rows) ----
#pragma unroll
  for (int mi = 0; mi < 2; ++mi) {
#pragma unroll
    for (int ni = 0; ni < 3; ++ni) {
      int col = ni * 16 + l15;
      if (col >= CLS) continue;
#pragma unroll
      for (int r = 0; r < 4; ++r) {
        int row = bm + wm + mi * 16 + lg * 4 + r;
        if (row < NN) h2p[(size_t)row * 64 + col] = to_fp8(acc[mi][ni][r]);
      }
    }
  }
}

// ---------------------------------------------------------------------------
// agg2: one wave per dst node; fp8 1B/lane gather (row = one 64B line);
// exp-dedup weights; fused bias + log_softmax.
// ---------------------------------------------------------------------------
__global__ __launch_bounds__(256) void k_agg2(const unsigned char* __restrict__ h2p,
                                              const float* __restrict__ asrc,
                                              const float* __restrict__ adst,
                                              const unsigned short* __restrict__ srcS,
                                              const int* __restrict__ rowptr,
                                              const float* __restrict__ b2,
                                              float* __restrict__ out) {
  int wave = (blockIdx.x * 256 + threadIdx.x) >> 6;
  int lane = threadIdx.x & 63;
  if (wave >= NN) return;
  int lo = rowptr[wave], hi = rowptr[wave + 1];
  bool act = lane < CLS;
  float adstv = adst[wave];
  float acc = 0.f, den = 0.f;

  for (int base = lo; base < hi; base += 64) {
    int cnt = hi - base; if (cnt > 64) cnt = 64;
    int sv = (lane < cnt) ? (int)srcS[base + lane] : 0;
    float v = asrc[sv] + adstv;
    v = v > 0.f ? v : 0.2f * v;
    float wv = __expf(v);
    int j = 0;
    for (; j + 8 <= cnt; j += 8) {
      int s[8]; float hval[8];
#pragma unroll
      for (int u = 0; u < 8; ++u) s[u] = __shfl(sv, j + u);
#pragma unroll
      for (int u = 0; u < 8; ++u)
        hval[u] = act ? from_fp8(h2p[(size_t)s[u] * 64 + lane]) : 0.f;
#pragma unroll
      for (int u = 0; u < 8; ++u) {
        float wu = __shfl(wv, j + u);
        acc += wu * hval[u];
        den += wu;
      }
    }
    for (; j < cnt; ++j) {
      int s = __shfl(sv, j);
      float wu = __shfl(wv, j);
      if (act) acc += wu * from_fp8(h2p[(size_t)s * 64 + lane]);
      den += wu;
    }
  }

  float o = act ? (acc / (den + 1e-16f) + b2[lane]) : -INFINITY;
  float m = o;
#pragma unroll
  for (int off = 32; off; off >>= 1) m = fmaxf(m, __shfl_xor(m, off, 64));
  float ex = act ? __expf(o - m) : 0.f;
  float ssum = ex;
#pragma unroll
  for (int off = 32; off; off >>= 1) ssum += __shfl_xor(ssum, off, 64);
  if (act) out[(size_t)wave * CLS + lane] = o - m - logf(ssum);
}

// ---------------------------------------------------------------------------
extern "C" void kernel_launch(void* const* d_in, const int* in_sizes, int n_in,
                              void* d_out, int out_size, void* d_ws, size_t ws_size,
                              hipStream_t stream) {
  const float* x      = (const float*)d_in[0];
  const int*   ei     = (const int*)d_in[1];
  const float* W1     = (const float*)d_in[2];
  const float* a_src1 = (const float*)d_in[3];
  const float* a_dst1 = (const float*)d_in[4];
  const float* b1     = (const float*)d_in[5];
  const float* W2     = (const float*)d_in[6];
  const float* a_src2 = (const float*)d_in[7];
  const float* a_dst2 = (const float*)d_in[8];
  const float* b2     = (const float*)d_in[9];
  float* out = (float*)d_out;

  char* p = (char*)d_ws;
  auto alloc = [&](size_t bytes) {
    char* r = p;
    p += (bytes + 255) & ~size_t(255);
    return r;
  };
  unsigned char* h1f8 = (unsigned char*)alloc((size_t)NN * HC);   // 12.8 MB
  __bf16* helu  = (__bf16*)alloc((size_t)NN * HC * 2);     // 25.6 MB
  __bf16* Wt    = (__bf16*)alloc((size_t)HC * FIN * 2);    // 256 KB
  __bf16* W2t   = (__bf16*)alloc((size_t)CLSP * HC * 2);   // 24 KB
  unsigned char* h2p = (unsigned char*)alloc((size_t)NN * 64);   // 3.2 MB
  float*  asrc1 = (float*)alloc((size_t)NN * NH * 4);
  float*  adst1 = (float*)alloc((size_t)NN * NH * 4);
  float*  asrc2 = (float*)alloc((size_t)NN * 4);
  float*  adst2 = (float*)alloc((size_t)NN * 4);
  unsigned short* srcS = (unsigned short*)alloc((size_t)EP * 2);  // 1.7 MB
  int*    deg   = (int*)alloc((size_t)NN * 4);
  int*    cursor= (int*)alloc((size_t)NN * 4);
  int*    rowptr= (int*)alloc((size_t)(NN + 1) * 4);
  int*    bsum  = (int*)alloc(256 * 4);

  hipMemsetAsync(deg, 0, (size_t)NN * 4, stream);

  const int nbScan = (NN + 1023) / 1024;  // 49
  k_prep<<<NSCB + CVTW_B, 256, 0, stream>>>(ei, deg, W1, W2, Wt, W2t);
  k_scan1<<<nbScan, 1024, 0, stream>>>(deg, rowptr + 1, bsum, NN);
  k_scan2<<<1, 64, 0, stream>>>(bsum, nbScan);
  k_scan3<<<(NN + 255) / 256, 256, 0, stream>>>(rowptr, bsum, cursor, NN);

  // fused: gemm1 (blocks 0..NGB-1) || csr scatter (blocks NGB..)
  k_gemm1_scatter<<<NGB + NSCB, 256, 0, stream>>>(x, Wt, a_src1, a_dst1,
                                                  h1f8, asrc1, adst1,
                                                  ei, cursor, srcS);

  k_agg1<<<(NN + 3) / 4, 256, 0, stream>>>(h1f8, asrc1, adst1, srcS, rowptr, b1, helu);

  k_gemm2m<<<(NN + 127) / 128, 256, 0, stream>>>(helu, W2t, a_src2, a_dst2,
                                                 h2p, asrc2, adst2);

  k_agg2<<<(NN + 3) / 4, 256, 0, stream>>>(h2p, asrc2, adst2, srcS, rowptr, b2, out);
}

// Round 15
// 193.569 us; speedup vs baseline: 1.1964x; 1.1692x over previous
//
#include <hip/hip_runtime.h>
#include <hip/hip_bf16.h>
#include <math.h>

// Problem constants (from reference)
constexpr int NN  = 50000;          // nodes
constexpr int NE  = 800000;         // edges (before self loops)
constexpr int EP  = NE + NN;        // edges + self loops = 850000
constexpr int FIN = 512;
constexpr int NH  = 8;
constexpr int NC  = 32;
constexpr int HC  = NH * NC;        // 256
constexpr int CLS = 40;
constexpr int CLSP = 48;            // padded classes for MFMA
constexpr int NGB  = (NN + 63) / 64;     // 782 gemm blocks
constexpr int NSCB = (EP + 255) / 256;   // 3321 edge blocks (1 edge/thread)
constexpr int DEGB = (NN + 255) / 256;   // 196 deg-zero blocks
constexpr int CVTW_ITEMS = HC * (FIN / 8) + CLSP * HC;  // 28672
constexpr int CVTW_B = (CVTW_ITEMS + 255) / 256;        // 112

typedef __attribute__((ext_vector_type(8))) __bf16 bf16x8;
typedef __attribute__((ext_vector_type(4))) __bf16 bf16x4;
typedef __attribute__((ext_vector_type(4))) float f32x4;
typedef __attribute__((ext_vector_type(2))) float f32x2;

__device__ inline bf16x8 cvt8v(const f32x4 a, const f32x4 b) {
  bf16x8 o;
  o[0] = (__bf16)a.x; o[1] = (__bf16)a.y; o[2] = (__bf16)a.z; o[3] = (__bf16)a.w;
  o[4] = (__bf16)b.x; o[5] = (__bf16)b.y; o[6] = (__bf16)b.z; o[7] = (__bf16)b.w;
  return o;
}

__device__ inline unsigned char to_fp8(float f) {
  int pk = __builtin_amdgcn_cvt_pk_fp8_f32(f, f, 0, false);
  return (unsigned char)(pk & 0xff);
}

__device__ inline float from_fp8(unsigned char b) {
  f32x2 v = __builtin_amdgcn_cvt_pk_f32_fp8((unsigned)b, false);
  return v.x;
}

// ---------------------------------------------------------------------------
// k_pre0: deg zeroing (blocks [0,DEGB)) + weight cvt (rest).
// ---------------------------------------------------------------------------
__global__ void k_pre0(int* __restrict__ deg,
                       const float* __restrict__ W1, const float* __restrict__ W2,
                       __bf16* __restrict__ Wt, __bf16* __restrict__ W2t) {
  if (blockIdx.x < DEGB) {
    int i = blockIdx.x * 256 + threadIdx.x;
    if (i < NN) deg[i] = 0;
    return;
  }
  int t = (blockIdx.x - DEGB) * 256 + threadIdx.x;
  if (t < HC * (FIN / 8)) {                      // 256 * 64
    int c = t >> 6, kq = (t & 63) * 8;
    bf16x8 o;
#pragma unroll
    for (int j = 0; j < 8; ++j) o[j] = (__bf16)W1[(size_t)(kq + j) * HC + c];
    *(bf16x8*)&Wt[(size_t)c * FIN + kq] = o;
  } else if (t < CVTW_ITEMS) {
    int u = t - HC * (FIN / 8);                  // 48 * 256
    int c = u >> 8, k = u & 255;
    W2t[u] = (c < CLS) ? (__bf16)W2[(size_t)k * CLS + c] : (__bf16)0.f;
  }
}

// ---------------------------------------------------------------------------
// FUSED-A: blocks [0,NGB) = GEMM1 (bf16 MFMA, fp8 out, fused alpha1);
//          blocks [NGB,NGB+NSCB) = rank-hist: rank[e]=atomicAdd(&deg[d],1)
// (one returning atomic per edge -- gives BOTH histogram and in-dst slot).
// GEMM: BM=64, BN=256, 4 waves; X staged as fp32 panel via global_load_lds
// w=16, double-buffered 32 KB. B direct-from-L2 Wt.
// ---------------------------------------------------------------------------
__global__ __launch_bounds__(256) void k_gemm1_hist(
    const float* __restrict__ X, const __bf16* __restrict__ Wt,
    const float* __restrict__ a_s1, const float* __restrict__ a_d1,
    unsigned char* __restrict__ Hout, float* __restrict__ asrc1,
    float* __restrict__ adst1,
    const int* __restrict__ ei, int* __restrict__ deg,
    int* __restrict__ rank) {
  __shared__ __align__(16) float Xp[2][4096];   // 2 x 16 KB
  const int tid = threadIdx.x;

  if (blockIdx.x >= NGB) {
    int e = (blockIdx.x - NGB) * 256 + tid;
    if (e < EP) {
      int d = (e < NE) ? ei[NE + e] : (e - NE);
      rank[e] = atomicAdd(&deg[d], 1);
    }
    return;
  }

  const int lane = tid & 63;
  const int w    = tid >> 6;              // wave 0..3
  const int wn   = w * 64;
  const int bm   = blockIdx.x * 64;
  const int l15  = lane & 15, lg = lane >> 4;

  const int srow_l  = (lane >> 4);            // row within inst 0..3
  const int sslot   = (l15 >> 1);             // slot 0..7
  const int shalf   = (lane & 1);

  f32x4 acc[4][4] = {};

  auto issue = [&](int c, int buf) {
#pragma unroll
    for (int jj = 0; jj < 4; ++jj) {
      const int j = w * 4 + jj;               // inst 0..15
      const int row_l = 4 * j + srow_l;       // 0..63
      const int rowG = min(bm + row_l, NN - 1);
      const int g = sslot ^ (row_l & 7);      // inverse swizzle
      const float* src = X + (size_t)rowG * FIN + c * 64 + g * 8 + shalf * 4;
      __builtin_amdgcn_global_load_lds(
          (const __attribute__((address_space(1))) void*)src,
          (__attribute__((address_space(3))) void*)(&Xp[buf][j * 256]), 16, 0, 0);
    }
  };

  issue(0, 0);
  for (int c = 0; c < 8; ++c) {
    const int cur = c & 1;
    __syncthreads();
    if (c < 7) issue(c + 1, cur ^ 1);

#pragma unroll
    for (int kh = 0; kh < 2; ++kh) {
      const int kb = lg + 4 * kh;             // 0..7
      bf16x8 bv[4];
#pragma unroll
      for (int ni = 0; ni < 4; ++ni)
        bv[ni] = *(const bf16x8*)(Wt + (size_t)(wn + ni * 16 + l15) * FIN
                                     + c * 64 + kb * 8);
#pragma unroll
      for (int mi = 0; mi < 4; ++mi) {
        int r = mi * 16 + l15;
        int fo = r * 64 + ((kb ^ (r & 7)) << 3);
        f32x4 alo = *(const f32x4*)&Xp[cur][fo];
        f32x4 ahi = *(const f32x4*)&Xp[cur][fo + 4];
        bf16x8 av = cvt8v(alo, ahi);
#pragma unroll
        for (int ni = 0; ni < 4; ++ni)
          acc[mi][ni] = __builtin_amdgcn_mfma_f32_16x16x32_bf16(
              av, bv[ni], acc[mi][ni], 0, 0, 0);
      }
    }
    __syncthreads();
  }

  // ---- fused alpha1 (heads 2w, 2w+1) ----
  const int hbase = 2 * w;
#pragma unroll
  for (int hh = 0; hh < 2; ++hh) {
    float asA = a_s1[(hbase + hh) * NC + l15];
    float asB = a_s1[(hbase + hh) * NC + 16 + l15];
    float adA = a_d1[(hbase + hh) * NC + l15];
    float adB = a_d1[(hbase + hh) * NC + 16 + l15];
    float vs = 0.f, vd = 0.f;
#pragma unroll
    for (int mi = 0; mi < 4; ++mi) {
#pragma unroll
      for (int r = 0; r < 4; ++r) {
        float ps = acc[mi][2 * hh][r] * asA + acc[mi][2 * hh + 1][r] * asB;
        float pd = acc[mi][2 * hh][r] * adA + acc[mi][2 * hh + 1][r] * adB;
#pragma unroll
        for (int off = 1; off < 16; off <<= 1) {
          ps += __shfl_xor(ps, off, 64);
          pd += __shfl_xor(pd, off, 64);
        }
        if (l15 == mi * 4 + r) { vs = ps; vd = pd; }
      }
    }
    int rw = bm + (l15 >> 2) * 16 + lg * 4 + (l15 & 3);
    if (rw < NN) {
      asrc1[(size_t)rw * NH + hbase + hh] = vs;
      adst1[(size_t)rw * NH + hbase + hh] = vd;
    }
  }

  // ---- h1 store as fp8 ----
#pragma unroll
  for (int mi = 0; mi < 4; ++mi) {
#pragma unroll
    for (int ni = 0; ni < 4; ++ni) {
      int col = wn + ni * 16 + l15;
#pragma unroll
      for (int r = 0; r < 4; ++r) {
        int row = bm + mi * 16 + lg * 4 + r;
        if (row < NN) Hout[(size_t)row * HC + col] = to_fp8(acc[mi][ni][r]);
      }
    }
  }
}

__global__ __launch_bounds__(1024) void k_scan1(const int* __restrict__ deg,
                                                int* __restrict__ rowptr1,
                                                int* __restrict__ bsum, int n) {
  __shared__ int sm[1024];
  int i = blockIdx.x * 1024 + threadIdx.x;
  int v = (i < n) ? deg[i] : 0;
  sm[threadIdx.x] = v;
  __syncthreads();
  for (int off = 1; off < 1024; off <<= 1) {
    int t = (threadIdx.x >= off) ? sm[threadIdx.x - off] : 0;
    __syncthreads();
    sm[threadIdx.x] += t;
    __syncthreads();
  }
  if (i < n) rowptr1[i] = sm[threadIdx.x];
  if (threadIdx.x == 1023) bsum[blockIdx.x] = sm[1023];
}

__global__ void k_scan2(int* __restrict__ bsum, int nb) {
  int lane = threadIdx.x;
  int v = (lane < nb) ? bsum[lane] : 0;
#pragma unroll
  for (int off = 1; off < 64; off <<= 1) {
    int t = __shfl_up(v, off);
    if (lane >= off) v += t;
  }
  int ex = __shfl_up(v, 1);
  if (lane == 0) ex = 0;
  if (lane < nb) bsum[lane] = ex;
}

__global__ void k_scan3(int* __restrict__ rowptr, const int* __restrict__ bsum, int n) {
  int i = blockIdx.x * 256 + threadIdx.x;
  if (i == 0) rowptr[0] = 0;
  if (i < n) rowptr[i + 1] += bsum[i >> 10];
}

// ---------------------------------------------------------------------------
// k_pass2: positional scatter, NO atomics: srcS[rowptr[d]+rank[e]] = src.
// ---------------------------------------------------------------------------
__global__ void k_pass2(const int* __restrict__ ei, const int* __restrict__ rank,
                        const int* __restrict__ rowptr,
                        unsigned short* __restrict__ srcS) {
  int e = blockIdx.x * 256 + threadIdx.x;
  if (e >= EP) return;
  int s, d;
  if (e < NE) { s = ei[e]; d = ei[NE + e]; } else { s = d = e - NE; }
  srcS[rowptr[d] + rank[e]] = (unsigned short)s;
}

// ---------------------------------------------------------------------------
// agg1: one wave per dst node; fp8x4 gather; exp-dedup; 8-deep MLP.
// ---------------------------------------------------------------------------
__global__ __launch_bounds__(256) void k_agg1(const unsigned char* __restrict__ h1f8,
                                              const float* __restrict__ asrc,
                                              const float* __restrict__ adst,
                                              const unsigned short* __restrict__ srcS,
                                              const int* __restrict__ rowptr,
                                              const float* __restrict__ b1,
                                              __bf16* __restrict__ helu) {
  int wave = (blockIdx.x * 256 + threadIdx.x) >> 6;
  int lane = threadIdx.x & 63;
  if (wave >= NN) return;
  int lo = rowptr[wave], hi = rowptr[wave + 1];
  int head = lane >> 3;
  int hw   = lane & 7;
  float adstv = adst[wave * NH + head];
  float ad2   = adst[wave * NH + hw];
  float4 acc = {0.f, 0.f, 0.f, 0.f};
  float den = 0.f;

  for (int base = lo; base < hi; base += 64) {
    int cnt = hi - base; if (cnt > 64) cnt = 64;
    int sv = (lane < cnt) ? (int)srcS[base + lane] : 0;
    int j = 0;
    for (; j + 8 <= cnt; j += 8) {
      int se = __shfl(sv, j + head);
      float v = asrc[se * NH + hw] + ad2;
      v = v > 0.f ? v : 0.2f * v;
      float wv = __expf(v);
      int s[8]; unsigned int hv[8];
#pragma unroll
      for (int u = 0; u < 8; ++u) s[u] = __shfl(sv, j + u);
#pragma unroll
      for (int u = 0; u < 8; ++u)
        hv[u] = *(const unsigned int*)&h1f8[(size_t)s[u] * HC + lane * 4];
#pragma unroll
      for (int u = 0; u < 8; ++u) {
        float wu = __shfl(wv, u * 8 + head);
        f32x2 lo2 = __builtin_amdgcn_cvt_pk_f32_fp8(hv[u], false);
        f32x2 hi2 = __builtin_amdgcn_cvt_pk_f32_fp8(hv[u], true);
        acc.x += wu * lo2.x;
        acc.y += wu * lo2.y;
        acc.z += wu * hi2.x;
        acc.w += wu * hi2.y;
        den += wu;
      }
    }
    for (; j < cnt; ++j) {
      int s = __shfl(sv, j);
      float v = asrc[s * NH + head] + adstv;
      v = v > 0.f ? v : 0.2f * v;
      float w = __expf(v);
      unsigned int hv = *(const unsigned int*)&h1f8[(size_t)s * HC + lane * 4];
      f32x2 lo2 = __builtin_amdgcn_cvt_pk_f32_fp8(hv, false);
      f32x2 hi2 = __builtin_amdgcn_cvt_pk_f32_fp8(hv, true);
      acc.x += w * lo2.x;
      acc.y += w * lo2.y;
      acc.z += w * hi2.x;
      acc.w += w * hi2.y;
      den += w;
    }
  }

  float inv = 1.f / (den + 1e-16f);
  float4 bb = *(const float4*)&b1[lane * 4];
  float o[4] = {acc.x * inv + bb.x, acc.y * inv + bb.y,
                acc.z * inv + bb.z, acc.w * inv + bb.w};
  bf16x4 ov;
#pragma unroll
  for (int j2 = 0; j2 < 4; ++j2) {
    float e = o[j2] > 0.f ? o[j2] : expm1f(o[j2]);
    ov[j2] = (__bf16)e;
  }
  *(bf16x4*)&helu[(size_t)wave * HC + lane * 4] = ov;
}

// ---------------------------------------------------------------------------
// GEMM2 (bf16 MFMA): h2p[NN,64](fp8 padded rows) = helu @ W2t^T + alpha2.
// ---------------------------------------------------------------------------
__global__ __launch_bounds__(256) void k_gemm2m(const __bf16* __restrict__ A,
                                                const __bf16* __restrict__ W2t,
                                                const float* __restrict__ a_s2,
                                                const float* __restrict__ a_d2,
                                                unsigned char* __restrict__ h2p,
                                                float* __restrict__ asrc2,
                                                float* __restrict__ adst2) {
  __shared__ __align__(16) __bf16 As[128 * 8 * 8];       // 16 KB
  __shared__ __align__(16) __bf16 Bsh[CLSP * 33 * 8];    // 25.3 KB padded
  const int tid  = threadIdx.x;
  const int lane = tid & 63;
  const int w    = tid >> 6;
  const int wm   = w * 32;
  const int bm   = blockIdx.x * 128;

  const int l3 = lane >> 3;
  const int l7 = lane & 7;
  const int kb_src = l7 ^ l3;

  for (int s = tid; s < CLSP * 32; s += 256) {
    int c = s >> 5, kb = s & 31;
    *(bf16x8*)(Bsh + (size_t)(c * 33 + kb) * 8) =
        *(const bf16x8*)(W2t + (size_t)c * HC + kb * 8);
  }

  f32x4 acc[2][3] = {};

  for (int step = 0; step < 4; ++step) {
    const int k0 = step * 64;
#pragma unroll
    for (int q = 0; q < 4; ++q) {
      const int inst = w * 4 + q;
      const int r = inst * 8 + l3;
      const int arow = min(bm + r, NN - 1);
      const __bf16* ga = A + (size_t)arow * HC + k0 + kb_src * 8;
      __builtin_amdgcn_global_load_lds(
          (const __attribute__((address_space(1))) void*)ga,
          (__attribute__((address_space(3))) void*)(As + inst * 512), 16, 0, 0);
    }
    __syncthreads();

    const int l15 = lane & 15, lg = lane >> 4;
#pragma unroll
    for (int kh = 0; kh < 2; ++kh) {
      const int kbl = lg + 4 * kh;
      const int kbg = step * 8 + kbl;
      bf16x8 av[2], bv[3];
#pragma unroll
      for (int mi = 0; mi < 2; ++mi) {
        int r = wm + mi * 16 + l15;
        av[mi] = *(const bf16x8*)(As + (size_t)(r * 8 + (kbl ^ (r & 7))) * 8);
      }
#pragma unroll
      for (int ni = 0; ni < 3; ++ni) {
        int c = ni * 16 + l15;
        bv[ni] = *(const bf16x8*)(Bsh + (size_t)(c * 33 + kbg) * 8);
      }
#pragma unroll
      for (int mi = 0; mi < 2; ++mi)
#pragma unroll
        for (int ni = 0; ni < 3; ++ni)
          acc[mi][ni] = __builtin_amdgcn_mfma_f32_16x16x32_bf16(
              av[mi], bv[ni], acc[mi][ni], 0, 0, 0);
    }
    __syncthreads();
  }

  const int l15 = lane & 15, lg = lane >> 4;

  // ---- fused alpha2 ----
  {
    int c0 = l15, c1 = 16 + l15, c2 = 32 + l15;
    float as0 = a_s2[c0], as1 = a_s2[c1], as2v = (c2 < CLS) ? a_s2[c2] : 0.f;
    float ad0 = a_d2[c0], ad1 = a_d2[c1], ad2v = (c2 < CLS) ? a_d2[c2] : 0.f;
    float vs = 0.f, vd = 0.f;
#pragma unroll
    for (int mi = 0; mi < 2; ++mi) {
#pragma unroll
      for (int r = 0; r < 4; ++r) {
        float ps = acc[mi][0][r] * as0 + acc[mi][1][r] * as1 + acc[mi][2][r] * as2v;
        float pd = acc[mi][0][r] * ad0 + acc[mi][1][r] * ad1 + acc[mi][2][r] * ad2v;
#pragma unroll
        for (int off = 1; off < 16; off <<= 1) {
          ps += __shfl_xor(ps, off, 64);
          pd += __shfl_xor(pd, off, 64);
        }
        if (l15 == mi * 4 + r) { vs = ps; vd = pd; }
      }
    }
    int rw = bm + wm + (l15 >> 2) * 16 + lg * 4 + (l15 & 3);
    if (l15 < 8 && rw < NN) {
      asrc2[rw] = vs;
      adst2[rw] = vd;
    }
  }

  // ---- h2p store (fp8, 64B-padded rows) ----
#pragma unroll
  for (int mi = 0; mi < 2; ++mi) {
#pragma unroll
    for (int ni = 0; ni < 3; ++ni) {
      int col = ni * 16 + l15;
      if (col >= CLS) continue;
#pragma unroll
      for (int r = 0; r < 4; ++r) {
        int row = bm + wm + mi * 16 + lg * 4 + r;
        if (row < NN) h2p[(size_t)row * 64 + col] = to_fp8(acc[mi][ni][r]);
      }
    }
  }
}

// ---------------------------------------------------------------------------
// agg2: one wave per dst node; fp8 1B/lane gather (row = one 64B line);
// exp-dedup weights; fused bias + log_softmax.
// ---------------------------------------------------------------------------
__global__ __launch_bounds__(256) void k_agg2(const unsigned char* __restrict__ h2p,
                                              const float* __restrict__ asrc,
                                              const float* __restrict__ adst,
                                              const unsigned short* __restrict__ srcS,
                                              const int* __restrict__ rowptr,
                                              const float* __restrict__ b2,
                                              float* __restrict__ out) {
  int wave = (blockIdx.x * 256 + threadIdx.x) >> 6;
  int lane = threadIdx.x & 63;
  if (wave >= NN) return;
  int lo = rowptr[wave], hi = rowptr[wave + 1];
  bool act = lane < CLS;
  float adstv = adst[wave];
  float acc = 0.f, den = 0.f;

  for (int base = lo; base < hi; base += 64) {
    int cnt = hi - base; if (cnt > 64) cnt = 64;
    int sv = (lane < cnt) ? (int)srcS[base + lane] : 0;
    float v = asrc[sv] + adstv;
    v = v > 0.f ? v : 0.2f * v;
    float wv = __expf(v);
    int j = 0;
    for (; j + 8 <= cnt; j += 8) {
      int s[8]; float hval[8];
#pragma unroll
      for (int u = 0; u < 8; ++u) s[u] = __shfl(sv, j + u);
#pragma unroll
      for (int u = 0; u < 8; ++u)
        hval[u] = act ? from_fp8(h2p[(size_t)s[u] * 64 + lane]) : 0.f;
#pragma unroll
      for (int u = 0; u < 8; ++u) {
        float wu = __shfl(wv, j + u);
        acc += wu * hval[u];
        den += wu;
      }
    }
    for (; j < cnt; ++j) {
      int s = __shfl(sv, j);
      float wu = __shfl(wv, j);
      if (act) acc += wu * from_fp8(h2p[(size_t)s * 64 + lane]);
      den += wu;
    }
  }

  float o = act ? (acc / (den + 1e-16f) + b2[lane]) : -INFINITY;
  float m = o;
#pragma unroll
  for (int off = 32; off; off >>= 1) m = fmaxf(m, __shfl_xor(m, off, 64));
  float ex = act ? __expf(o - m) : 0.f;
  float ssum = ex;
#pragma unroll
  for (int off = 32; off; off >>= 1) ssum += __shfl_xor(ssum, off, 64);
  if (act) out[(size_t)wave * CLS + lane] = o - m - logf(ssum);
}

// ---------------------------------------------------------------------------
extern "C" void kernel_launch(void* const* d_in, const int* in_sizes, int n_in,
                              void* d_out, int out_size, void* d_ws, size_t ws_size,
                              hipStream_t stream) {
  const float* x      = (const float*)d_in[0];
  const int*   ei     = (const int*)d_in[1];
  const float* W1     = (const float*)d_in[2];
  const float* a_src1 = (const float*)d_in[3];
  const float* a_dst1 = (const float*)d_in[4];
  const float* b1     = (const float*)d_in[5];
  const float* W2     = (const float*)d_in[6];
  const float* a_src2 = (const float*)d_in[7];
  const float* a_dst2 = (const float*)d_in[8];
  const float* b2     = (const float*)d_in[9];
  float* out = (float*)d_out;

  char* p = (char*)d_ws;
  auto alloc = [&](size_t bytes) {
    char* r = p;
    p += (bytes + 255) & ~size_t(255);
    return r;
  };
  unsigned char* h1f8 = (unsigned char*)alloc((size_t)NN * HC);   // 12.8 MB
  __bf16* helu  = (__bf16*)alloc((size_t)NN * HC * 2);     // 25.6 MB
  __bf16* Wt    = (__bf16*)alloc((size_t)HC * FIN * 2);    // 256 KB
  __bf16* W2t   = (__bf16*)alloc((size_t)CLSP * HC * 2);   // 24 KB
  unsigned char* h2p = (unsigned char*)alloc((size_t)NN * 64);   // 3.2 MB
  float*  asrc1 = (float*)alloc((size_t)NN * NH * 4);
  float*  adst1 = (float*)alloc((size_t)NN * NH * 4);
  float*  asrc2 = (float*)alloc((size_t)NN * 4);
  float*  adst2 = (float*)alloc((size_t)NN * 4);
  unsigned short* srcS = (unsigned short*)alloc((size_t)EP * 2);  // 1.7 MB
  int*    rank  = (int*)alloc((size_t)EP * 4);             // 3.4 MB
  int*    deg   = (int*)alloc((size_t)NN * 4);
  int*    rowptr= (int*)alloc((size_t)(NN + 1) * 4);
  int*    bsum  = (int*)alloc(256 * 4);

  const int nbScan = (NN + 1023) / 1024;  // 49

  // 1. deg zero + weight cvt
  k_pre0<<<DEGB + CVTW_B, 256, 0, stream>>>(deg, W1, W2, Wt, W2t);

  // 2. FUSED-A: gemm1 || rank-hist (one returning atomic per edge)
  k_gemm1_hist<<<NGB + NSCB, 256, 0, stream>>>(x, Wt, a_src1, a_dst1,
                                               h1f8, asrc1, adst1,
                                               ei, deg, rank);

  // 3. rowptr scans
  k_scan1<<<nbScan, 1024, 0, stream>>>(deg, rowptr + 1, bsum, NN);
  k_scan2<<<1, 64, 0, stream>>>(bsum, nbScan);
  k_scan3<<<(NN + 255) / 256, 256, 0, stream>>>(rowptr, bsum, NN);

  // 4. positional scatter (no atomics)
  k_pass2<<<NSCB, 256, 0, stream>>>(ei, rank, rowptr, srcS);

  // 5-7. aggregation + layer 2
  k_agg1<<<(NN + 3) / 4, 256, 0, stream>>>(h1f8, asrc1, adst1, srcS, rowptr, b1, helu);

  k_gemm2m<<<(NN + 127) / 128, 256, 0, stream>>>(helu, W2t, a_src2, a_dst2,
                                                 h2p, asrc2, adst2);

  k_agg2<<<(NN + 3) / 4, 256, 0, stream>>>(h2p, asrc2, adst2, srcS, rowptr, b2, out);
}

// Round 16
// 191.845 us; speedup vs baseline: 1.2071x; 1.0090x over previous
//
#include <hip/hip_runtime.h>
#include <hip/hip_bf16.h>
#include <math.h>

// Problem constants (from reference)
constexpr int NN  = 50000;          // nodes
constexpr int NE  = 800000;         // edges (before self loops)
constexpr int EP  = NE + NN;        // edges + self loops = 850000
constexpr int FIN = 512;
constexpr int NH  = 8;
constexpr int NC  = 32;
constexpr int HC  = NH * NC;        // 256
constexpr int CLS = 40;
constexpr int CLSP = 48;            // padded classes for MFMA
constexpr int NGB  = (NN + 63) / 64;     // 782 gemm blocks
constexpr int NSCB = (EP + 255) / 256;   // 3321 edge blocks (1 edge/thread)
constexpr int DEGB = (NN + 255) / 256;   // 196 deg-zero blocks
constexpr int CVTW_ITEMS = HC * (FIN / 8) + CLSP * HC;  // 28672
constexpr int CVTW_B = (CVTW_ITEMS + 255) / 256;        // 112

typedef __attribute__((ext_vector_type(8))) __bf16 bf16x8;
typedef __attribute__((ext_vector_type(4))) __bf16 bf16x4;
typedef __attribute__((ext_vector_type(4))) float f32x4;
typedef __attribute__((ext_vector_type(2))) float f32x2;

__device__ inline bf16x8 cvt8v(const f32x4 a, const f32x4 b) {
  bf16x8 o;
  o[0] = (__bf16)a.x; o[1] = (__bf16)a.y; o[2] = (__bf16)a.z; o[3] = (__bf16)a.w;
  o[4] = (__bf16)b.x; o[5] = (__bf16)b.y; o[6] = (__bf16)b.z; o[7] = (__bf16)b.w;
  return o;
}

__device__ inline unsigned char to_fp8(float f) {
  int pk = __builtin_amdgcn_cvt_pk_fp8_f32(f, f, 0, false);
  return (unsigned char)(pk & 0xff);
}

__device__ inline float from_fp8(unsigned char b) {
  f32x2 v = __builtin_amdgcn_cvt_pk_f32_fp8((unsigned)b, false);
  return v.x;
}

// ---------------------------------------------------------------------------
// k_pre0: deg zeroing (blocks [0,DEGB)) + weight cvt (rest).
// ---------------------------------------------------------------------------
__global__ void k_pre0(int* __restrict__ deg,
                       const float* __restrict__ W1, const float* __restrict__ W2,
                       __bf16* __restrict__ Wt, __bf16* __restrict__ W2t) {
  if (blockIdx.x < DEGB) {
    int i = blockIdx.x * 256 + threadIdx.x;
    if (i < NN) deg[i] = 0;
    return;
  }
  int t = (blockIdx.x - DEGB) * 256 + threadIdx.x;
  if (t < HC * (FIN / 8)) {                      // 256 * 64
    int c = t >> 6, kq = (t & 63) * 8;
    bf16x8 o;
#pragma unroll
    for (int j = 0; j < 8; ++j) o[j] = (__bf16)W1[(size_t)(kq + j) * HC + c];
    *(bf16x8*)&Wt[(size_t)c * FIN + kq] = o;
  } else if (t < CVTW_ITEMS) {
    int u = t - HC * (FIN / 8);                  // 48 * 256
    int c = u >> 8, k = u & 255;
    W2t[u] = (c < CLS) ? (__bf16)W2[(size_t)k * CLS + c] : (__bf16)0.f;
  }
}

// ---------------------------------------------------------------------------
// FUSED-A: blocks [0,NGB) = GEMM1 (bf16 MFMA, fp8 out, fused alpha1);
//          blocks [NGB,NGB+NSCB) = rank-hist: rank[e]=atomicAdd(&deg[d],1).
// GEMM: BM=64, BN=256, 4 waves; X staged as fp32 panel via global_load_lds
// w=16, double-buffered 32 KB. ONE barrier per chunk: each wave's implicit
// vmcnt(0) at the barrier covers its own prefetch portion, so chunk c+1's
// loads (issued right after the barrier) hide under compute(c) -- true
// 1-deep pipeline. B direct-from-L2 Wt.
// ---------------------------------------------------------------------------
__global__ __launch_bounds__(256) void k_gemm1_hist(
    const float* __restrict__ X, const __bf16* __restrict__ Wt,
    const float* __restrict__ a_s1, const float* __restrict__ a_d1,
    unsigned char* __restrict__ Hout, float* __restrict__ asrc1,
    float* __restrict__ adst1,
    const int* __restrict__ ei, int* __restrict__ deg,
    int* __restrict__ rank) {
  __shared__ __align__(16) float Xp[2][4096];   // 2 x 16 KB
  const int tid = threadIdx.x;

  if (blockIdx.x >= NGB) {
    int e = (blockIdx.x - NGB) * 256 + tid;
    if (e < EP) {
      int d = (e < NE) ? ei[NE + e] : (e - NE);
      rank[e] = atomicAdd(&deg[d], 1);
    }
    return;
  }

  const int lane = tid & 63;
  const int w    = tid >> 6;              // wave 0..3
  const int wn   = w * 64;
  const int bm   = blockIdx.x * 64;
  const int l15  = lane & 15, lg = lane >> 4;

  const int srow_l  = (lane >> 4);            // row within inst 0..3
  const int sslot   = (l15 >> 1);             // slot 0..7
  const int shalf   = (lane & 1);

  f32x4 acc[4][4] = {};

  auto issue = [&](int c, int buf) {
#pragma unroll
    for (int jj = 0; jj < 4; ++jj) {
      const int j = w * 4 + jj;               // inst 0..15
      const int row_l = 4 * j + srow_l;       // 0..63
      const int rowG = min(bm + row_l, NN - 1);
      const int g = sslot ^ (row_l & 7);      // inverse swizzle
      const float* src = X + (size_t)rowG * FIN + c * 64 + g * 8 + shalf * 4;
      __builtin_amdgcn_global_load_lds(
          (const __attribute__((address_space(1))) void*)src,
          (__attribute__((address_space(3))) void*)(&Xp[buf][j * 256]), 16, 0, 0);
    }
  };

  issue(0, 0);
  for (int c = 0; c < 8; ++c) {
    const int cur = c & 1;
    __syncthreads();            // per-wave vmcnt(0) + barrier: buf[cur] ready;
                                // buf[cur] not rewritten until all waves pass
    if (c < 7) issue(c + 1, cur ^ 1);

#pragma unroll
    for (int kh = 0; kh < 2; ++kh) {
      const int kb = lg + 4 * kh;             // 0..7
      bf16x8 bv[4];
#pragma unroll
      for (int ni = 0; ni < 4; ++ni)
        bv[ni] = *(const bf16x8*)(Wt + (size_t)(wn + ni * 16 + l15) * FIN
                                     + c * 64 + kb * 8);
#pragma unroll
      for (int mi = 0; mi < 4; ++mi) {
        int r = mi * 16 + l15;
        int fo = r * 64 + ((kb ^ (r & 7)) << 3);
        f32x4 alo = *(const f32x4*)&Xp[cur][fo];
        f32x4 ahi = *(const f32x4*)&Xp[cur][fo + 4];
        bf16x8 av = cvt8v(alo, ahi);
#pragma unroll
        for (int ni = 0; ni < 4; ++ni)
          acc[mi][ni] = __builtin_amdgcn_mfma_f32_16x16x32_bf16(
              av, bv[ni], acc[mi][ni], 0, 0, 0);
      }
    }
    // NOTE: no trailing barrier -- the top-of-loop barrier provides the
    // write-after-read fence for buf[cur] (all waves have finished compute
    // by the time any wave issues into it again).
  }

  // ---- fused alpha1 (heads 2w, 2w+1) ----
  const int hbase = 2 * w;
#pragma unroll
  for (int hh = 0; hh < 2; ++hh) {
    float asA = a_s1[(hbase + hh) * NC + l15];
    float asB = a_s1[(hbase + hh) * NC + 16 + l15];
    float adA = a_d1[(hbase + hh) * NC + l15];
    float adB = a_d1[(hbase + hh) * NC + 16 + l15];
    float vs = 0.f, vd = 0.f;
#pragma unroll
    for (int mi = 0; mi < 4; ++mi) {
#pragma unroll
      for (int r = 0; r < 4; ++r) {
        float ps = acc[mi][2 * hh][r] * asA + acc[mi][2 * hh + 1][r] * asB;
        float pd = acc[mi][2 * hh][r] * adA + acc[mi][2 * hh + 1][r] * adB;
#pragma unroll
        for (int off = 1; off < 16; off <<= 1) {
          ps += __shfl_xor(ps, off, 64);
          pd += __shfl_xor(pd, off, 64);
        }
        if (l15 == mi * 4 + r) { vs = ps; vd = pd; }
      }
    }
    int rw = bm + (l15 >> 2) * 16 + lg * 4 + (l15 & 3);
    if (rw < NN) {
      asrc1[(size_t)rw * NH + hbase + hh] = vs;
      adst1[(size_t)rw * NH + hbase + hh] = vd;
    }
  }

  // ---- h1 store as fp8 ----
#pragma unroll
  for (int mi = 0; mi < 4; ++mi) {
#pragma unroll
    for (int ni = 0; ni < 4; ++ni) {
      int col = wn + ni * 16 + l15;
#pragma unroll
      for (int r = 0; r < 4; ++r) {
        int row = bm + mi * 16 + lg * 4 + r;
        if (row < NN) Hout[(size_t)row * HC + col] = to_fp8(acc[mi][ni][r]);
      }
    }
  }
}

__global__ __launch_bounds__(1024) void k_scan1(const int* __restrict__ deg,
                                                int* __restrict__ rowptr1,
                                                int* __restrict__ bsum, int n) {
  __shared__ int sm[1024];
  int i = blockIdx.x * 1024 + threadIdx.x;
  int v = (i < n) ? deg[i] : 0;
  sm[threadIdx.x] = v;
  __syncthreads();
  for (int off = 1; off < 1024; off <<= 1) {
    int t = (threadIdx.x >= off) ? sm[threadIdx.x - off] : 0;
    __syncthreads();
    sm[threadIdx.x] += t;
    __syncthreads();
  }
  if (i < n) rowptr1[i] = sm[threadIdx.x];
  if (threadIdx.x == 1023) bsum[blockIdx.x] = sm[1023];
}

// merged scan2+scan3: each block re-scans the <=64 block sums in-wave, then
// adds the exclusive offset to its rowptr slice.
__global__ void k_scan23(int* __restrict__ rowptr, const int* __restrict__ bsum,
                         int nb, int n) {
  __shared__ int off[64];
  if (threadIdx.x < 64) {
    int lane = threadIdx.x;
    int v = (lane < nb) ? bsum[lane] : 0;
#pragma unroll
    for (int o = 1; o < 64; o <<= 1) {
      int t = __shfl_up(v, o);
      if (lane >= o) v += t;
    }
    int ex = __shfl_up(v, 1);
    if (lane == 0) ex = 0;
    off[lane] = ex;
  }
  __syncthreads();
  int i = blockIdx.x * 256 + threadIdx.x;
  if (i == 0) rowptr[0] = 0;
  if (i < n) rowptr[i + 1] += off[i >> 10];
}

// ---------------------------------------------------------------------------
// k_pass2: positional scatter, NO atomics: srcS[rowptr[d]+rank[e]] = src.
// ---------------------------------------------------------------------------
__global__ void k_pass2(const int* __restrict__ ei, const int* __restrict__ rank,
                        const int* __restrict__ rowptr,
                        unsigned short* __restrict__ srcS) {
  int e = blockIdx.x * 256 + threadIdx.x;
  if (e >= EP) return;
  int s, d;
  if (e < NE) { s = ei[e]; d = ei[NE + e]; } else { s = d = e - NE; }
  srcS[rowptr[d] + rank[e]] = (unsigned short)s;
}

// ---------------------------------------------------------------------------
// agg1: one wave per dst node; fp8x4 gather; exp-dedup; 8-deep MLP.
// ---------------------------------------------------------------------------
__global__ __launch_bounds__(256) void k_agg1(const unsigned char* __restrict__ h1f8,
                                              const float* __restrict__ asrc,
                                              const float* __restrict__ adst,
                                              const unsigned short* __restrict__ srcS,
                                              const int* __restrict__ rowptr,
                                              const float* __restrict__ b1,
                                              __bf16* __restrict__ helu) {
  int wave = (blockIdx.x * 256 + threadIdx.x) >> 6;
  int lane = threadIdx.x & 63;
  if (wave >= NN) return;
  int lo = rowptr[wave], hi = rowptr[wave + 1];
  int head = lane >> 3;
  int hw   = lane & 7;
  float adstv = adst[wave * NH + head];
  float ad2   = adst[wave * NH + hw];
  float4 acc = {0.f, 0.f, 0.f, 0.f};
  float den = 0.f;

  for (int base = lo; base < hi; base += 64) {
    int cnt = hi - base; if (cnt > 64) cnt = 64;
    int sv = (lane < cnt) ? (int)srcS[base + lane] : 0;
    int j = 0;
    for (; j + 8 <= cnt; j += 8) {
      int se = __shfl(sv, j + head);
      float v = asrc[se * NH + hw] + ad2;
      v = v > 0.f ? v : 0.2f * v;
      float wv = __expf(v);
      int s[8]; unsigned int hv[8];
#pragma unroll
      for (int u = 0; u < 8; ++u) s[u] = __shfl(sv, j + u);
#pragma unroll
      for (int u = 0; u < 8; ++u)
        hv[u] = *(const unsigned int*)&h1f8[(size_t)s[u] * HC + lane * 4];
#pragma unroll
      for (int u = 0; u < 8; ++u) {
        float wu = __shfl(wv, u * 8 + head);
        f32x2 lo2 = __builtin_amdgcn_cvt_pk_f32_fp8(hv[u], false);
        f32x2 hi2 = __builtin_amdgcn_cvt_pk_f32_fp8(hv[u], true);
        acc.x += wu * lo2.x;
        acc.y += wu * lo2.y;
        acc.z += wu * hi2.x;
        acc.w += wu * hi2.y;
        den += wu;
      }
    }
    for (; j < cnt; ++j) {
      int s = __shfl(sv, j);
      float v = asrc[s * NH + head] + adstv;
      v = v > 0.f ? v : 0.2f * v;
      float w = __expf(v);
      unsigned int hv = *(const unsigned int*)&h1f8[(size_t)s * HC + lane * 4];
      f32x2 lo2 = __builtin_amdgcn_cvt_pk_f32_fp8(hv, false);
      f32x2 hi2 = __builtin_amdgcn_cvt_pk_f32_fp8(hv, true);
      acc.x += w * lo2.x;
      acc.y += w * lo2.y;
      acc.z += w * hi2.x;
      acc.w += w * hi2.y;
      den += w;
    }
  }

  float inv = 1.f / (den + 1e-16f);
  float4 bb = *(const float4*)&b1[lane * 4];
  float o[4] = {acc.x * inv + bb.x, acc.y * inv + bb.y,
                acc.z * inv + bb.z, acc.w * inv + bb.w};
  bf16x4 ov;
#pragma unroll
  for (int j2 = 0; j2 < 4; ++j2) {
    float e = o[j2] > 0.f ? o[j2] : expm1f(o[j2]);
    ov[j2] = (__bf16)e;
  }
  *(bf16x4*)&helu[(size_t)wave * HC + lane * 4] = ov;
}

// ---------------------------------------------------------------------------
// GEMM2 (bf16 MFMA): h2p[NN,64](fp8 padded rows) = helu @ W2t^T + alpha2.
// ---------------------------------------------------------------------------
__global__ __launch_bounds__(256) void k_gemm2m(const __bf16* __restrict__ A,
                                                const __bf16* __restrict__ W2t,
                                                const float* __restrict__ a_s2,
                                                const float* __restrict__ a_d2,
                                                unsigned char* __restrict__ h2p,
                                                float* __restrict__ asrc2,
                                                float* __restrict__ adst2) {
  __shared__ __align__(16) __bf16 As[128 * 8 * 8];       // 16 KB
  __shared__ __align__(16) __bf16 Bsh[CLSP * 33 * 8];    // 25.3 KB padded
  const int tid  = threadIdx.x;
  const int lane = tid & 63;
  const int w    = tid >> 6;
  const int wm   = w * 32;
  const int bm   = blockIdx.x * 128;

  const int l3 = lane >> 3;
  const int l7 = lane & 7;
  const int kb_src = l7 ^ l3;

  for (int s = tid; s < CLSP * 32; s += 256) {
    int c = s >> 5, kb = s & 31;
    *(bf16x8*)(Bsh + (size_t)(c * 33 + kb) * 8) =
        *(const bf16x8*)(W2t + (size_t)c * HC + kb * 8);
  }

  f32x4 acc[2][3] = {};

  for (int step = 0; step < 4; ++step) {
    const int k0 = step * 64;
#pragma unroll
    for (int q = 0; q < 4; ++q) {
      const int inst = w * 4 + q;
      const int r = inst * 8 + l3;
      const int arow = min(bm + r, NN - 1);
      const __bf16* ga = A + (size_t)arow * HC + k0 + kb_src * 8;
      __builtin_amdgcn_global_load_lds(
          (const __attribute__((address_space(1))) void*)ga,
          (__attribute__((address_space(3))) void*)(As + inst * 512), 16, 0, 0);
    }
    __syncthreads();

    const int l15 = lane & 15, lg = lane >> 4;
#pragma unroll
    for (int kh = 0; kh < 2; ++kh) {
      const int kbl = lg + 4 * kh;
      const int kbg = step * 8 + kbl;
      bf16x8 av[2], bv[3];
#pragma unroll
      for (int mi = 0; mi < 2; ++mi) {
        int r = wm + mi * 16 + l15;
        av[mi] = *(const bf16x8*)(As + (size_t)(r * 8 + (kbl ^ (r & 7))) * 8);
      }
#pragma unroll
      for (int ni = 0; ni < 3; ++ni) {
        int c = ni * 16 + l15;
        bv[ni] = *(const bf16x8*)(Bsh + (size_t)(c * 33 + kbg) * 8);
      }
#pragma unroll
      for (int mi = 0; mi < 2; ++mi)
#pragma unroll
        for (int ni = 0; ni < 3; ++ni)
          acc[mi][ni] = __builtin_amdgcn_mfma_f32_16x16x32_bf16(
              av[mi], bv[ni], acc[mi][ni], 0, 0, 0);
    }
    __syncthreads();
  }

  const int l15 = lane & 15, lg = lane >> 4;

  // ---- fused alpha2 ----
  {
    int c0 = l15, c1 = 16 + l15, c2 = 32 + l15;
    float as0 = a_s2[c0], as1 = a_s2[c1], as2v = (c2 < CLS) ? a_s2[c2] : 0.f;
    float ad0 = a_d2[c0], ad1 = a_d2[c1], ad2v = (c2 < CLS) ? a_d2[c2] : 0.f;
    float vs = 0.f, vd = 0.f;
#pragma unroll
    for (int mi = 0; mi < 2; ++mi) {
#pragma unroll
      for (int r = 0; r < 4; ++r) {
        float ps = acc[mi][0][r] * as0 + acc[mi][1][r] * as1 + acc[mi][2][r] * as2v;
        float pd = acc[mi][0][r] * ad0 + acc[mi][1][r] * ad1 + acc[mi][2][r] * ad2v;
#pragma unroll
        for (int off = 1; off < 16; off <<= 1) {
          ps += __shfl_xor(ps, off, 64);
          pd += __shfl_xor(pd, off, 64);
        }
        if (l15 == mi * 4 + r) { vs = ps; vd = pd; }
      }
    }
    int rw = bm + wm + (l15 >> 2) * 16 + lg * 4 + (l15 & 3);
    if (l15 < 8 && rw < NN) {
      asrc2[rw] = vs;
      adst2[rw] = vd;
    }
  }

  // ---- h2p store (fp8, 64B-padded rows) ----
#pragma unroll
  for (int mi = 0; mi < 2; ++mi) {
#pragma unroll
    for (int ni = 0; ni < 3; ++ni) {
      int col = ni * 16 + l15;
      if (col >= CLS) continue;
#pragma unroll
      for (int r = 0; r < 4; ++r) {
        int row = bm + wm + mi * 16 + lg * 4 + r;
        if (row < NN) h2p[(size_t)row * 64 + col] = to_fp8(acc[mi][ni][r]);
      }
    }
  }
}

// ---------------------------------------------------------------------------
// agg2: one wave per dst node; fp8 1B/lane gather (row = one 64B line);
// exp-dedup weights; fused bias + log_softmax.
// ---------------------------------------------------------------------------
__global__ __launch_bounds__(256) void k_agg2(const unsigned char* __restrict__ h2p,
                                              const float* __restrict__ asrc,
                                              const float* __restrict__ adst,
                                              const unsigned short* __restrict__ srcS,
                                              const int* __restrict__ rowptr,
                                              const float* __restrict__ b2,
                                              float* __restrict__ out) {
  int wave = (blockIdx.x * 256 + threadIdx.x) >> 6;
  int lane = threadIdx.x & 63;
  if (wave >= NN) return;
  int lo = rowptr[wave], hi = rowptr[wave + 1];
  bool act = lane < CLS;
  float adstv = adst[wave];
  float acc = 0.f, den = 0.f;

  for (int base = lo; base < hi; base += 64) {
    int cnt = hi - base; if (cnt > 64) cnt = 64;
    int sv = (lane < cnt) ? (int)srcS[base + lane] : 0;
    float v = asrc[sv] + adstv;
    v = v > 0.f ? v : 0.2f * v;
    float wv = __expf(v);
    int j = 0;
    for (; j + 8 <= cnt; j += 8) {
      int s[8]; float hval[8];
#pragma unroll
      for (int u = 0; u < 8; ++u) s[u] = __shfl(sv, j + u);
#pragma unroll
      for (int u = 0; u < 8; ++u)
        hval[u] = act ? from_fp8(h2p[(size_t)s[u] * 64 + lane]) : 0.f;
#pragma unroll
      for (int u = 0; u < 8; ++u) {
        float wu = __shfl(wv, j + u);
        acc += wu * hval[u];
        den += wu;
      }
    }
    for (; j < cnt; ++j) {
      int s = __shfl(sv, j);
      float wu = __shfl(wv, j);
      if (act) acc += wu * from_fp8(h2p[(size_t)s * 64 + lane]);
      den += wu;
    }
  }

  float o = act ? (acc / (den + 1e-16f) + b2[lane]) : -INFINITY;
  float m = o;
#pragma unroll
  for (int off = 32; off; off >>= 1) m = fmaxf(m, __shfl_xor(m, off, 64));
  float ex = act ? __expf(o - m) : 0.f;
  float ssum = ex;
#pragma unroll
  for (int off = 32; off; off >>= 1) ssum += __shfl_xor(ssum, off, 64);
  if (act) out[(size_t)wave * CLS + lane] = o - m - logf(ssum);
}

// ---------------------------------------------------------------------------
extern "C" void kernel_launch(void* const* d_in, const int* in_sizes, int n_in,
                              void* d_out, int out_size, void* d_ws, size_t ws_size,
                              hipStream_t stream) {
  const float* x      = (const float*)d_in[0];
  const int*   ei     = (const int*)d_in[1];
  const float* W1     = (const float*)d_in[2];
  const float* a_src1 = (const float*)d_in[3];
  const float* a_dst1 = (const float*)d_in[4];
  const float* b1     = (const float*)d_in[5];
  const float* W2     = (const float*)d_in[6];
  const float* a_src2 = (const float*)d_in[7];
  const float* a_dst2 = (const float*)d_in[8];
  const float* b2     = (const float*)d_in[9];
  float* out = (float*)d_out;

  char* p = (char*)d_ws;
  auto alloc = [&](size_t bytes) {
    char* r = p;
    p += (bytes + 255) & ~size_t(255);
    return r;
  };
  unsigned char* h1f8 = (unsigned char*)alloc((size_t)NN * HC);   // 12.8 MB
  __bf16* helu  = (__bf16*)alloc((size_t)NN * HC * 2);     // 25.6 MB
  __bf16* Wt    = (__bf16*)alloc((size_t)HC * FIN * 2);    // 256 KB
  __bf16* W2t   = (__bf16*)alloc((size_t)CLSP * HC * 2);   // 24 KB
  unsigned char* h2p = (unsigned char*)alloc((size_t)NN * 64);   // 3.2 MB
  float*  asrc1 = (float*)alloc((size_t)NN * NH * 4);
  float*  adst1 = (float*)alloc((size_t)NN * NH * 4);
  float*  asrc2 = (float*)alloc((size_t)NN * 4);
  float*  adst2 = (float*)alloc((size_t)NN * 4);
  unsigned short* srcS = (unsigned short*)alloc((size_t)EP * 2);  // 1.7 MB
  int*    rank  = (int*)alloc((size_t)EP * 4);             // 3.4 MB
  int*    deg   = (int*)alloc((size_t)NN * 4);
  int*    rowptr= (int*)alloc((size_t)(NN + 1) * 4);
  int*    bsum  = (int*)alloc(256 * 4);

  const int nbScan = (NN + 1023) / 1024;  // 49

  // 1. deg zero + weight cvt
  k_pre0<<<DEGB + CVTW_B, 256, 0, stream>>>(deg, W1, W2, Wt, W2t);

  // 2. FUSED-A: gemm1 || rank-hist
  k_gemm1_hist<<<NGB + NSCB, 256, 0, stream>>>(x, Wt, a_src1, a_dst1,
                                               h1f8, asrc1, adst1,
                                               ei, deg, rank);

  // 3. rowptr scans (scan2 folded into scan23)
  k_scan1<<<nbScan, 1024, 0, stream>>>(deg, rowptr + 1, bsum, NN);
  k_scan23<<<(NN + 255) / 256, 256, 0, stream>>>(rowptr, bsum, nbScan, NN);

  // 4. positional scatter (no atomics)
  k_pass2<<<NSCB, 256, 0, stream>>>(ei, rank, rowptr, srcS);

  // 5-7. aggregation + layer 2
  k_agg1<<<(NN + 3) / 4, 256, 0, stream>>>(h1f8, asrc1, adst1, srcS, rowptr, b1, helu);

  k_gemm2m<<<(NN + 127) / 128, 256, 0, stream>>>(helu, W2t, a_src2, a_dst2,
                                                 h2p, asrc2, adst2);

  k_agg2<<<(NN + 3) / 4, 256, 0, stream>>>(h2p, asrc2, adst2, srcS, rowptr, b2, out);
}